// Round 2
// baseline (1243.435 us; speedup 1.0000x reference)
//
#include <hip/hip_runtime.h>

// Self-attention, B=4, N=4096, D=256 (single head over full D).
//   Q = x Wq^T + bq ; K,V likewise ; S = Q K^T ; mask==0 -> -inf ;
//   attn = softmax(S/16) ; out = attn V        (fp32 in/out)
// R12: flash is latency-bound, not BW-bound (all pipes <15%, 8400cy/tile
//   vs ~1400cy of work; occupancy 21% = 2 blocks/CU, LDS-capped by the
//   75KB K/P double-buffers). Fix: SINGLE-buffer Klds and Plds.
//   B2 (post-P barrier) already proves all QK reads of K(t) are done, so
//   K(t+1) stages into the same buffer post-B2; B1 vmcnt(8) proves it
//   landed. B1 likewise separates PV reads from next tile's P writes.
//   LDS 75->37.6KB => 4 blocks/CU (16 waves/CU, 4/SIMD) at VGPR=128.
//   FIFO (steady): top=[M(t+1)] -> +V(t) -> QK/P/B2 -> +K(t+1) -> +M(t+2)
//   =32 -> vmcnt(16) retires M(t+1),V(t) -> PV -> B1 vmcnt(8) retires K.
//   vmcnt(24) order-tie dropped (masks retired by prev tile's vmcnt(16)).
//   Post-loop vmcnt(0) drain added (in-flight M loads vs reg reuse).
// ws: Qs bf16 8MiB | Kb bf16 8MiB | Vt bf16 8MiB | Wp 384KiB

#define DEV static __device__ __forceinline__

typedef __attribute__((ext_vector_type(8))) short bf8;   // 8 bf16 (4 VGPR)
typedef __attribute__((ext_vector_type(4))) float f4;
typedef const __attribute__((address_space(1))) unsigned int* gp1;
typedef __attribute__((address_space(3))) unsigned int* lp3;

DEV short f2bf(float x) {  // fp32 -> bf16 RNE (inputs finite)
  unsigned u = __builtin_bit_cast(unsigned, x);
  u += 0x7FFFu + ((u >> 16) & 1u);
  return (short)(u >> 16);
}

DEV bf8 cvt8(f4 a, f4 b) {
  bf8 r;
  r[0] = f2bf(a[0]); r[1] = f2bf(a[1]); r[2] = f2bf(a[2]); r[3] = f2bf(a[3]);
  r[4] = f2bf(b[0]); r[5] = f2bf(b[1]); r[6] = f2bf(b[2]); r[7] = f2bf(b[3]);
  return r;
}

DEV bf8 cvtp(const float* p) { return cvt8(*(const f4*)p, *(const f4*)(p + 4)); }

DEV f4 mfma16(bf8 a, bf8 b, f4 c) {
  return __builtin_amdgcn_mfma_f32_16x16x32_bf16(a, b, c, 0, 0, 0);
}

DEV void gl_lds16(const void* g, void* l) {  // async global->LDS, 16B/lane
  __builtin_amdgcn_global_load_lds((gp1)g, (lp3)l, 16, 0, 0);
}

DEV void ld16(bf8& d, const short* p) {  // unsinkable 16B global load
  __asm__ __volatile__("global_load_dwordx4 %0, %1, off" : "=v"(d) : "v"(p));
}
DEV void ld4nt(int& d, const int* p) {   // unsinkable 4B global load, NT
  __asm__ __volatile__("global_load_dword %0, %1, off nt" : "=v"(d) : "v"(p));
}

// ---------------- kernel 0: pack W -> bf16 fragment-order (R9) ------------
__global__ void pack(const float* __restrict__ Wq, const float* __restrict__ Wk,
                     const float* __restrict__ Wv, short* __restrict__ Wp) {
  const int ch = blockIdx.x * 4 + (threadIdx.x >> 6);
  const int lane = threadIdx.x & 63;
  const int which = ch >> 7, rem = ch & 127;
  const int w = rem >> 5, e = (rem >> 3) & 3, ks = rem & 7;
  const float* W = (which == 0) ? Wq : (which == 1) ? Wk : Wv;
  bf8 v = cvtp(W + ((w * 4 + e) * 16 + (lane & 15)) * 256 + ks * 32 +
               (lane >> 4) * 8);
  *(bf8*)(Wp + ch * 512 + lane * 8) = v;
}

// ---------------- kernel 1: Q,K,V projection (R9) -------------------------
__launch_bounds__(256, 3)
__global__ void qkv(const float* __restrict__ x, const short* __restrict__ Wp,
                    const float* __restrict__ bq, const float* __restrict__ bk,
                    const float* __restrict__ bv, short* __restrict__ Qs,
                    short* __restrict__ Kb, short* __restrict__ Vt) {
  __shared__ float Xf[32 * 256];    // x tile, swizzled, 32KB
  __shared__ short Vlds[256 * 36];  // V transpose staging (which==2 only)
  const int which = blockIdx.y;
  const int m0 = blockIdx.x * 32;
  const int tid = threadIdx.x;
  const int w = tid >> 6, lane = tid & 63, quad = lane >> 4, c = lane & 15;
  const float* bias = (which == 0) ? bq : (which == 1) ? bk : bv;

#pragma unroll
  for (int l = 0; l < 8; l++) {
    const int row = l * 4 + (tid >> 6);
    const int kch = tid & 63;
    const int chg = (kch & 48) | ((kch ^ (row & 15)) & 15);  // involutive
    gl_lds16(x + (m0 + row) * 256 + chg * 4, &Xf[(l * 256 + tid) * 4]);
  }

  float bb[4];
#pragma unroll
  for (int e = 0; e < 4; e++) bb[e] = bias[(w * 4 + e) * 16 + c];

  f4 acc[2][4];
  const f4 z = {0.f, 0.f, 0.f, 0.f};
#pragma unroll
  for (int i = 0; i < 2; i++)
#pragma unroll
    for (int j = 0; j < 4; j++) acc[i][j] = z;

  __asm__ __volatile__("s_waitcnt vmcnt(0)\ns_barrier" ::: "memory");

  const short* wpb = Wp + (which * 4 + w) * 4 * 8 * 512;
#pragma unroll
  for (int ks = 0; ks < 8; ks++) {
    bf8 a[2], b[4];
#pragma unroll
    for (int ms = 0; ms < 2; ms++) {  // A[m=lane&15][k=quad*8+j]
      const int m = ms * 16 + c;
      const int ch0 = ks * 8 + quad * 2;
      const int sw0 = (ch0 & 48) | ((ch0 ^ c) & 15);
      const int sw1 = ((ch0 + 1) & 48) | (((ch0 + 1) ^ c) & 15);
      f4 f0 = *(const f4*)&Xf[m * 256 + sw0 * 4];
      f4 f1 = *(const f4*)&Xf[m * 256 + sw1 * 4];
      a[ms] = cvt8(f0, f1);
    }
#pragma unroll
    for (int e = 0; e < 4; e++)
      b[e] = *(const bf8*)(wpb + (e * 8 + ks) * 512 + lane * 8);
#pragma unroll
    for (int ms = 0; ms < 2; ms++)
#pragma unroll
      for (int e = 0; e < 4; e++) acc[ms][e] = mfma16(a[ms], b[e], acc[ms][e]);
  }

  const float sc = (which == 0) ? 0.09016844005556021f : 1.0f;  // log2e/16

  if (which < 2) {
    short* dst = (which == 0) ? Qs : Kb;
#pragma unroll
    for (int ms = 0; ms < 2; ms++)
#pragma unroll
      for (int e = 0; e < 4; e++)
#pragma unroll
        for (int r = 0; r < 4; r++)  // C/D: col=lane&15, row=quad*4+reg
          dst[(m0 + ms * 16 + quad * 4 + r) * 256 + (w * 4 + e) * 16 + c] =
              f2bf((acc[ms][e][r] + bb[e]) * sc);
  } else {
#pragma unroll
    for (int ms = 0; ms < 2; ms++)
#pragma unroll
      for (int e = 0; e < 4; e++)
#pragma unroll
        for (int r = 0; r < 4; r++)
          Vlds[((w * 4 + e) * 16 + c) * 36 + ms * 16 + quad * 4 + r] =
              f2bf(acc[ms][e][r] + bb[e]);
    __syncthreads();
    const int tt = m0 >> 6, half = m0 & 32;
#pragma unroll
    for (int j = 0; j < 4; j++) {
      int flat = j * 2048 + tid * 8;        // 256 d x 32 n
      int d = flat >> 5, n = flat & 31;
      *(bf8*)(Vt + tt * 16384 + d * 64 + half + n) =
          *(const bf8*)&Vlds[d * 36 + n];
    }
  }
}

// ---------------- kernel 2: flash attention ----------------
// 512 WGs (4/CU). batch = bx&3. Steady-state tile t (manual 2-phase for
// mask reg dbuf only):
//  issue V(t) asm -> QK from Klds (K(t) proven by prev B1) ->
//  P=exp2(masked S) (mask regs, retired by prev vmcnt(16)) -> B2
//  (lgkm0+barrier: all QK reads done) -> stage K(t+1) gl_lds into the
//  SAME Klds -> issue M(t+2) asm NT -> vmcnt(16) [retires M(t+1),V(t)]
//  -> PV from Plds -> B1 (vmcnt(8)+barrier) [K(t+1) landed; M(t+2) flies].
// No compiler VM ops anywhere in the loop.
__launch_bounds__(256, 4)
__global__ void flash(const short* __restrict__ Qs, const short* __restrict__ Kb,
                      const short* __restrict__ Vt, const int* __restrict__ mask,
                      float* __restrict__ out) {
  __shared__ short Klds[16384];    // K single buf 64x256, swizzled, 32KB
  __shared__ short Plds[32 * 76];  // P single buf, stride 76 (conflict-free)
  const int bx = blockIdx.x;
  const int batch = bx & 3;
  const int q0 = (bx >> 2) * 32;
  const int tid = threadIdx.x;
  const int w = tid >> 6, lane = tid & 63, quad = lane >> 4, c = lane & 15;

  const short* kb = Kb + batch * 4096 * 256;
  const short* vb = Vt + batch * 1048576;
  const int* mb = mask + batch * 16777216;

  const int krow = tid >> 5;  // K staging: row-in-8-row-line (0..7)
  const int kch = tid & 31;   // LDS chunk this thread fills

  // ---- prologue: K(0)->Klds, M(0)->mA, M(1)->mB, Q via asm ----
#pragma unroll
  for (int l = 0; l < 8; l++) {
    const int row = l * 8 + krow;
    const int chg = (kch & 16) | ((kch ^ row) & 15);  // involutive swizzle
    gl_lds16(kb + row * 256 + chg * 8, &Klds[l * 2048 + tid * 8]);
  }
  int mA[8], mB[8];
#pragma unroll
  for (int ms = 0; ms < 2; ms++)
#pragma unroll
    for (int r = 0; r < 4; r++) {
      ld4nt(mA[ms * 4 + r], mb + (q0 + ms * 16 + quad * 4 + r) * 4096 + w * 16 + c);
      ld4nt(mB[ms * 4 + r],
            mb + (q0 + ms * 16 + quad * 4 + r) * 4096 + 64 + w * 16 + c);
    }
  bf8 aq[2][8];
  const short* qb = Qs + (batch * 4096 + q0) * 256;
#pragma unroll
  for (int ms = 0; ms < 2; ms++)
#pragma unroll
    for (int ks = 0; ks < 8; ks++)
      ld16(aq[ms][ks], qb + (ms * 16 + c) * 256 + ks * 32 + quad * 8);

  const f4 z = {0.f, 0.f, 0.f, 0.f};
  f4 accO[2][4], lacc[2];
#pragma unroll
  for (int ms = 0; ms < 2; ms++) {
    lacc[ms] = z;
#pragma unroll
    for (int ds = 0; ds < 4; ds++) accO[ms][ds] = z;
  }
  const bf8 ONES = {0x3F80, 0x3F80, 0x3F80, 0x3F80, 0x3F80, 0x3F80, 0x3F80, 0x3F80};

  // drain prologue; tie aq (16) + mA (8) = 24 operands
  __asm__ __volatile__("s_waitcnt vmcnt(0)\ns_barrier"
      : "+v"(aq[0][0]), "+v"(aq[0][1]), "+v"(aq[0][2]), "+v"(aq[0][3]),
        "+v"(aq[0][4]), "+v"(aq[0][5]), "+v"(aq[0][6]), "+v"(aq[0][7]),
        "+v"(aq[1][0]), "+v"(aq[1][1]), "+v"(aq[1][2]), "+v"(aq[1][3]),
        "+v"(aq[1][4]), "+v"(aq[1][5]), "+v"(aq[1][6]), "+v"(aq[1][7]),
        "+v"(mA[0]), "+v"(mA[1]), "+v"(mA[2]), "+v"(mA[3]),
        "+v"(mA[4]), "+v"(mA[5]), "+v"(mA[6]), "+v"(mA[7]) :: "memory");

  auto tile = [&](int t, int* mcur) {
    // ---- issue V(t) (asm regs) ----
    bf8 vc[2][4];
#pragma unroll
    for (int k2 = 0; k2 < 2; k2++)
#pragma unroll
      for (int ds = 0; ds < 4; ds++)
        ld16(vc[k2][ds], vb + t * 16384 + (w * 64 + ds * 16 + c) * 64 +
                         k2 * 32 + quad * 8);

    // ---- S = Q' K^T from swizzled Klds (K(t) proven by prev B1) ----
    f4 s[2];
#pragma unroll
    for (int ms = 0; ms < 2; ms++) s[ms] = z;
#pragma unroll
    for (int ks = 0; ks < 8; ks++) {
      const int ch = ks * 4 + quad;
      const int sw = (ch & 16) | ((ch ^ c) & 15);
      const bf8 kf = *(const bf8*)&Klds[(w * 16 + c) * 256 + sw * 8];
#pragma unroll
      for (int ms = 0; ms < 2; ms++) s[ms] = mfma16(aq[ms][ks], kf, s[ms]);
    }

    // ---- P = exp2(masked S) -> Plds (mask regs retired by prev vmcnt16) --
    short* pw = &Plds[0];
#pragma unroll
    for (int ms = 0; ms < 2; ms++)
#pragma unroll
      for (int r = 0; r < 4; r++) {
        float sv = (mcur[ms * 4 + r] != 0) ? s[ms][r] : -INFINITY;
        pw[(ms * 16 + quad * 4 + r) * 76 + w * 16 + c] =
            f2bf(__builtin_amdgcn_exp2f(sv));
      }
    // B2: P visible; all QK reads of K(t) complete across the block
    __asm__ __volatile__("s_waitcnt lgkmcnt(0)\ns_barrier" ::: "memory");

    // ---- stage K(t+1) into the SAME buffer (safe past B2) ----
    const int tk = (t < 63) ? t + 1 : 63;
    const short* kbt = kb + tk * 16384;
#pragma unroll
    for (int l = 0; l < 8; l++) {
      const int row = l * 8 + krow;
      const int chg = (kch & 16) | ((kch ^ row) & 15);
      gl_lds16(kbt + row * 256 + chg * 8, &Klds[l * 2048 + tid * 8]);
    }

    // ---- issue M(t+2) into mcur (P reads above done; reg WAR orders) ----
    const int tm = (t + 2 < 64) ? t + 2 : 63;
#pragma unroll
    for (int ms = 0; ms < 2; ms++)
#pragma unroll
      for (int r = 0; r < 4; r++)
        ld4nt(mcur[ms * 4 + r],
              mb + (q0 + ms * 16 + quad * 4 + r) * 4096 + tm * 64 + w * 16 + c);

    // ---- queue=[M(t+1):8,V(t):8,K(t+1):8,M(t+2):8]=32; vmcnt(16)
    //      retires M(t+1)+V(t). Leaves K(t+1)+M(t+2). ----
    __asm__ __volatile__("s_waitcnt vmcnt(16)"
        : "+v"(vc[0][0]), "+v"(vc[0][1]), "+v"(vc[0][2]), "+v"(vc[0][3]),
          "+v"(vc[1][0]), "+v"(vc[1][1]), "+v"(vc[1][2]), "+v"(vc[1][3]),
          "+v"(mA[0]), "+v"(mA[1]), "+v"(mA[2]), "+v"(mA[3]),
          "+v"(mA[4]), "+v"(mA[5]), "+v"(mA[6]), "+v"(mA[7]),
          "+v"(mB[0]), "+v"(mB[1]), "+v"(mB[2]), "+v"(mB[3]),
          "+v"(mB[4]), "+v"(mB[5]), "+v"(mB[6]), "+v"(mB[7]) :: "memory");

    // ---- O += P V ; row-sum via ones-frag MFMA ----
#pragma unroll
    for (int k2 = 0; k2 < 2; k2++) {
      bf8 ap[2];
#pragma unroll
      for (int ms = 0; ms < 2; ms++)  // A[m=lane&15][k=quad*8+j]
        ap[ms] = *(const bf8*)&pw[(ms * 16 + c) * 76 + k2 * 32 + quad * 8];
#pragma unroll
      for (int ms = 0; ms < 2; ms++) {
        lacc[ms] = mfma16(ap[ms], ONES, lacc[ms]);
#pragma unroll
        for (int ds = 0; ds < 4; ds++)
          accO[ms][ds] = mfma16(ap[ms], vc[k2][ds], accO[ms][ds]);
      }
    }
    // B1: K(t+1) landed in LDS; M(t+2) keeps flying; PV reads done for
    // every wave -> next tile may overwrite Plds
    __asm__ __volatile__("s_waitcnt vmcnt(8)\ns_barrier" ::: "memory");
  };

  for (int th = 0; th < 32; th++) {
    tile(2 * th, mA);
    tile(2 * th + 1, mB);
  }
  // drain in-flight tail M loads before epilogue reuses their registers
  __asm__ __volatile__("s_waitcnt vmcnt(0)" ::: "memory");

  // ---- epilogue: O / l ----
  float* ob = out + (batch * 4096 + q0) * 256;
#pragma unroll
  for (int ms = 0; ms < 2; ms++) {
    f4 rl;
#pragma unroll
    for (int r = 0; r < 4; r++) rl[r] = __builtin_amdgcn_rcpf(lacc[ms][r]);
#pragma unroll
    for (int ds = 0; ds < 4; ds++)
#pragma unroll
      for (int r = 0; r < 4; r++)
        ob[(ms * 16 + quad * 4 + r) * 256 + w * 64 + ds * 16 + c] =
            accO[ms][ds][r] * rl[r];
  }
}

extern "C" void kernel_launch(void* const* d_in, const int* in_sizes, int n_in,
                              void* d_out, int out_size, void* d_ws, size_t ws_size,
                              hipStream_t stream) {
  const float* x = (const float*)d_in[0];
  const int* mask = (const int*)d_in[1];
  const float* Wq = (const float*)d_in[2];
  const float* bq = (const float*)d_in[3];
  const float* Wk = (const float*)d_in[4];
  const float* bk = (const float*)d_in[5];
  const float* Wv = (const float*)d_in[6];
  const float* bv = (const float*)d_in[7];
  float* out = (float*)d_out;

  char* ws = (char*)d_ws;  // 24 MiB + 384 KiB
  short* Qs = (short*)ws;
  short* Kb = (short*)(ws + (8u << 20));
  short* Vt = (short*)(ws + (16u << 20));
  short* Wp = (short*)(ws + (24u << 20));

  pack<<<96, 256, 0, stream>>>(Wq, Wk, Wv, Wp);
  qkv<<<dim3(512, 3), 256, 0, stream>>>(x, Wp, bq, bk, bv, Qs, Kb, Vt);
  flash<<<512, 256, 0, stream>>>(Qs, Kb, Vt, mask, out);
}

// Round 3
// 1011.324 us; speedup vs baseline: 1.2295x; 1.2295x over previous
//
#include <hip/hip_runtime.h>

// Self-attention, B=4, N=4096, D=256 (single head over full D).
//   Q = x Wq^T + bq ; K,V likewise ; S = Q K^T ; mask==0 -> -inf ;
//   attn = softmax(S/16) ; out = attn V        (fp32 in/out)
// R13: R12's __launch_bounds__(256,4) capped unified VGPR+AGPR at 128/wave
//   vs ~168 live state -> massive scratch spill (FETCH 155MB->1.86GB,
//   WRITE 16->338MB, VGPR_Count 64) -> 941us. Occupancy theory untested.
//   Fix: (256,3) -> budget ~170 regs/wave = the same clean allocation as
//   (256,2) (128 VGPR + 40 AGPR, no spill). LDS is single-buffered at
//   37.9KB (R12 structure, correctness-proven), so occupancy should land
//   at 3 blocks/CU (12 waves/CU, 37.5%) vs baseline's 2 (21%).
//   Pipeline (unchanged from R12): issue V(t) -> QK from Klds -> P=exp2
//   -> B2 (lgkm0+barrier: QK reads done) -> stage K(t+1) into SAME Klds
//   -> issue M(t+2) NT -> vmcnt(16) [retires M(t+1),V(t)] -> PV -> B1
//   (vmcnt(8)+barrier) [K(t+1) landed].
// ws: Qs bf16 8MiB | Kb bf16 8MiB | Vt bf16 8MiB | Wp 384KiB

#define DEV static __device__ __forceinline__

typedef __attribute__((ext_vector_type(8))) short bf8;   // 8 bf16 (4 VGPR)
typedef __attribute__((ext_vector_type(4))) float f4;
typedef const __attribute__((address_space(1))) unsigned int* gp1;
typedef __attribute__((address_space(3))) unsigned int* lp3;

DEV short f2bf(float x) {  // fp32 -> bf16 RNE (inputs finite)
  unsigned u = __builtin_bit_cast(unsigned, x);
  u += 0x7FFFu + ((u >> 16) & 1u);
  return (short)(u >> 16);
}

DEV bf8 cvt8(f4 a, f4 b) {
  bf8 r;
  r[0] = f2bf(a[0]); r[1] = f2bf(a[1]); r[2] = f2bf(a[2]); r[3] = f2bf(a[3]);
  r[4] = f2bf(b[0]); r[5] = f2bf(b[1]); r[6] = f2bf(b[2]); r[7] = f2bf(b[3]);
  return r;
}

DEV bf8 cvtp(const float* p) { return cvt8(*(const f4*)p, *(const f4*)(p + 4)); }

DEV f4 mfma16(bf8 a, bf8 b, f4 c) {
  return __builtin_amdgcn_mfma_f32_16x16x32_bf16(a, b, c, 0, 0, 0);
}

DEV void gl_lds16(const void* g, void* l) {  // async global->LDS, 16B/lane
  __builtin_amdgcn_global_load_lds((gp1)g, (lp3)l, 16, 0, 0);
}

DEV void ld16(bf8& d, const short* p) {  // unsinkable 16B global load
  __asm__ __volatile__("global_load_dwordx4 %0, %1, off" : "=v"(d) : "v"(p));
}
DEV void ld4nt(int& d, const int* p) {   // unsinkable 4B global load, NT
  __asm__ __volatile__("global_load_dword %0, %1, off nt" : "=v"(d) : "v"(p));
}

// ---------------- kernel 0: pack W -> bf16 fragment-order (R9) ------------
__global__ void pack(const float* __restrict__ Wq, const float* __restrict__ Wk,
                     const float* __restrict__ Wv, short* __restrict__ Wp) {
  const int ch = blockIdx.x * 4 + (threadIdx.x >> 6);
  const int lane = threadIdx.x & 63;
  const int which = ch >> 7, rem = ch & 127;
  const int w = rem >> 5, e = (rem >> 3) & 3, ks = rem & 7;
  const float* W = (which == 0) ? Wq : (which == 1) ? Wk : Wv;
  bf8 v = cvtp(W + ((w * 4 + e) * 16 + (lane & 15)) * 256 + ks * 32 +
               (lane >> 4) * 8);
  *(bf8*)(Wp + ch * 512 + lane * 8) = v;
}

// ---------------- kernel 1: Q,K,V projection (R9) -------------------------
__launch_bounds__(256, 3)
__global__ void qkv(const float* __restrict__ x, const short* __restrict__ Wp,
                    const float* __restrict__ bq, const float* __restrict__ bk,
                    const float* __restrict__ bv, short* __restrict__ Qs,
                    short* __restrict__ Kb, short* __restrict__ Vt) {
  __shared__ float Xf[32 * 256];    // x tile, swizzled, 32KB
  __shared__ short Vlds[256 * 36];  // V transpose staging (which==2 only)
  const int which = blockIdx.y;
  const int m0 = blockIdx.x * 32;
  const int tid = threadIdx.x;
  const int w = tid >> 6, lane = tid & 63, quad = lane >> 4, c = lane & 15;
  const float* bias = (which == 0) ? bq : (which == 1) ? bk : bv;

#pragma unroll
  for (int l = 0; l < 8; l++) {
    const int row = l * 4 + (tid >> 6);
    const int kch = tid & 63;
    const int chg = (kch & 48) | ((kch ^ (row & 15)) & 15);  // involutive
    gl_lds16(x + (m0 + row) * 256 + chg * 4, &Xf[(l * 256 + tid) * 4]);
  }

  float bb[4];
#pragma unroll
  for (int e = 0; e < 4; e++) bb[e] = bias[(w * 4 + e) * 16 + c];

  f4 acc[2][4];
  const f4 z = {0.f, 0.f, 0.f, 0.f};
#pragma unroll
  for (int i = 0; i < 2; i++)
#pragma unroll
    for (int j = 0; j < 4; j++) acc[i][j] = z;

  __asm__ __volatile__("s_waitcnt vmcnt(0)\ns_barrier" ::: "memory");

  const short* wpb = Wp + (which * 4 + w) * 4 * 8 * 512;
#pragma unroll
  for (int ks = 0; ks < 8; ks++) {
    bf8 a[2], b[4];
#pragma unroll
    for (int ms = 0; ms < 2; ms++) {  // A[m=lane&15][k=quad*8+j]
      const int m = ms * 16 + c;
      const int ch0 = ks * 8 + quad * 2;
      const int sw0 = (ch0 & 48) | ((ch0 ^ c) & 15);
      const int sw1 = ((ch0 + 1) & 48) | (((ch0 + 1) ^ c) & 15);
      f4 f0 = *(const f4*)&Xf[m * 256 + sw0 * 4];
      f4 f1 = *(const f4*)&Xf[m * 256 + sw1 * 4];
      a[ms] = cvt8(f0, f1);
    }
#pragma unroll
    for (int e = 0; e < 4; e++)
      b[e] = *(const bf8*)(wpb + (e * 8 + ks) * 512 + lane * 8);
#pragma unroll
    for (int ms = 0; ms < 2; ms++)
#pragma unroll
      for (int e = 0; e < 4; e++) acc[ms][e] = mfma16(a[ms], b[e], acc[ms][e]);
  }

  const float sc = (which == 0) ? 0.09016844005556021f : 1.0f;  // log2e/16

  if (which < 2) {
    short* dst = (which == 0) ? Qs : Kb;
#pragma unroll
    for (int ms = 0; ms < 2; ms++)
#pragma unroll
      for (int e = 0; e < 4; e++)
#pragma unroll
        for (int r = 0; r < 4; r++)  // C/D: col=lane&15, row=quad*4+reg
          dst[(m0 + ms * 16 + quad * 4 + r) * 256 + (w * 4 + e) * 16 + c] =
              f2bf((acc[ms][e][r] + bb[e]) * sc);
  } else {
#pragma unroll
    for (int ms = 0; ms < 2; ms++)
#pragma unroll
      for (int e = 0; e < 4; e++)
#pragma unroll
        for (int r = 0; r < 4; r++)
          Vlds[((w * 4 + e) * 16 + c) * 36 + ms * 16 + quad * 4 + r] =
              f2bf(acc[ms][e][r] + bb[e]);
    __syncthreads();
    const int tt = m0 >> 6, half = m0 & 32;
#pragma unroll
    for (int j = 0; j < 4; j++) {
      int flat = j * 2048 + tid * 8;        // 256 d x 32 n
      int d = flat >> 5, n = flat & 31;
      *(bf8*)(Vt + tt * 16384 + d * 64 + half + n) =
          *(const bf8*)&Vlds[d * 36 + n];
    }
  }
}

// ---------------- kernel 2: flash attention ----------------
// 512 WGs (3/CU). batch = bx&3. Steady-state tile t (manual 2-phase for
// mask reg dbuf only):
//  issue V(t) asm -> QK from Klds (K(t) proven by prev B1) ->
//  P=exp2(masked S) (mask regs, retired by prev vmcnt(16)) -> B2
//  (lgkm0+barrier: all QK reads done) -> stage K(t+1) gl_lds into the
//  SAME Klds -> issue M(t+2) asm NT -> vmcnt(16) [retires M(t+1),V(t)]
//  -> PV from Plds -> B1 (vmcnt(8)+barrier) [K(t+1) landed; M(t+2) flies].
// No compiler VM ops anywhere in the loop.
__launch_bounds__(256, 3)
__global__ void flash(const short* __restrict__ Qs, const short* __restrict__ Kb,
                      const short* __restrict__ Vt, const int* __restrict__ mask,
                      float* __restrict__ out) {
  __shared__ short Klds[16384];    // K single buf 64x256, swizzled, 32KB
  __shared__ short Plds[32 * 76];  // P single buf, stride 76 (conflict-free)
  const int bx = blockIdx.x;
  const int batch = bx & 3;
  const int q0 = (bx >> 2) * 32;
  const int tid = threadIdx.x;
  const int w = tid >> 6, lane = tid & 63, quad = lane >> 4, c = lane & 15;

  const short* kb = Kb + batch * 4096 * 256;
  const short* vb = Vt + batch * 1048576;
  const int* mb = mask + batch * 16777216;

  const int krow = tid >> 5;  // K staging: row-in-8-row-line (0..7)
  const int kch = tid & 31;   // LDS chunk this thread fills

  // ---- prologue: K(0)->Klds, M(0)->mA, M(1)->mB, Q via asm ----
#pragma unroll
  for (int l = 0; l < 8; l++) {
    const int row = l * 8 + krow;
    const int chg = (kch & 16) | ((kch ^ row) & 15);  // involutive swizzle
    gl_lds16(kb + row * 256 + chg * 8, &Klds[l * 2048 + tid * 8]);
  }
  int mA[8], mB[8];
#pragma unroll
  for (int ms = 0; ms < 2; ms++)
#pragma unroll
    for (int r = 0; r < 4; r++) {
      ld4nt(mA[ms * 4 + r], mb + (q0 + ms * 16 + quad * 4 + r) * 4096 + w * 16 + c);
      ld4nt(mB[ms * 4 + r],
            mb + (q0 + ms * 16 + quad * 4 + r) * 4096 + 64 + w * 16 + c);
    }
  bf8 aq[2][8];
  const short* qb = Qs + (batch * 4096 + q0) * 256;
#pragma unroll
  for (int ms = 0; ms < 2; ms++)
#pragma unroll
    for (int ks = 0; ks < 8; ks++)
      ld16(aq[ms][ks], qb + (ms * 16 + c) * 256 + ks * 32 + quad * 8);

  const f4 z = {0.f, 0.f, 0.f, 0.f};
  f4 accO[2][4], lacc[2];
#pragma unroll
  for (int ms = 0; ms < 2; ms++) {
    lacc[ms] = z;
#pragma unroll
    for (int ds = 0; ds < 4; ds++) accO[ms][ds] = z;
  }
  const bf8 ONES = {0x3F80, 0x3F80, 0x3F80, 0x3F80, 0x3F80, 0x3F80, 0x3F80, 0x3F80};

  // drain prologue; tie aq (16) + mA (8) = 24 operands
  __asm__ __volatile__("s_waitcnt vmcnt(0)\ns_barrier"
      : "+v"(aq[0][0]), "+v"(aq[0][1]), "+v"(aq[0][2]), "+v"(aq[0][3]),
        "+v"(aq[0][4]), "+v"(aq[0][5]), "+v"(aq[0][6]), "+v"(aq[0][7]),
        "+v"(aq[1][0]), "+v"(aq[1][1]), "+v"(aq[1][2]), "+v"(aq[1][3]),
        "+v"(aq[1][4]), "+v"(aq[1][5]), "+v"(aq[1][6]), "+v"(aq[1][7]),
        "+v"(mA[0]), "+v"(mA[1]), "+v"(mA[2]), "+v"(mA[3]),
        "+v"(mA[4]), "+v"(mA[5]), "+v"(mA[6]), "+v"(mA[7]) :: "memory");

  auto tile = [&](int t, int* mcur) {
    // ---- issue V(t) (asm regs) ----
    bf8 vc[2][4];
#pragma unroll
    for (int k2 = 0; k2 < 2; k2++)
#pragma unroll
      for (int ds = 0; ds < 4; ds++)
        ld16(vc[k2][ds], vb + t * 16384 + (w * 64 + ds * 16 + c) * 64 +
                         k2 * 32 + quad * 8);

    // ---- S = Q' K^T from swizzled Klds (K(t) proven by prev B1) ----
    f4 s[2];
#pragma unroll
    for (int ms = 0; ms < 2; ms++) s[ms] = z;
#pragma unroll
    for (int ks = 0; ks < 8; ks++) {
      const int ch = ks * 4 + quad;
      const int sw = (ch & 16) | ((ch ^ c) & 15);
      const bf8 kf = *(const bf8*)&Klds[(w * 16 + c) * 256 + sw * 8];
#pragma unroll
      for (int ms = 0; ms < 2; ms++) s[ms] = mfma16(aq[ms][ks], kf, s[ms]);
    }

    // ---- P = exp2(masked S) -> Plds (mask regs retired by prev vmcnt16) --
    short* pw = &Plds[0];
#pragma unroll
    for (int ms = 0; ms < 2; ms++)
#pragma unroll
      for (int r = 0; r < 4; r++) {
        float sv = (mcur[ms * 4 + r] != 0) ? s[ms][r] : -INFINITY;
        pw[(ms * 16 + quad * 4 + r) * 76 + w * 16 + c] =
            f2bf(__builtin_amdgcn_exp2f(sv));
      }
    // B2: P visible; all QK reads of K(t) complete across the block
    __asm__ __volatile__("s_waitcnt lgkmcnt(0)\ns_barrier" ::: "memory");

    // ---- stage K(t+1) into the SAME buffer (safe past B2) ----
    const int tk = (t < 63) ? t + 1 : 63;
    const short* kbt = kb + tk * 16384;
#pragma unroll
    for (int l = 0; l < 8; l++) {
      const int row = l * 8 + krow;
      const int chg = (kch & 16) | ((kch ^ row) & 15);
      gl_lds16(kbt + row * 256 + chg * 8, &Klds[l * 2048 + tid * 8]);
    }

    // ---- issue M(t+2) into mcur (P reads above done; reg WAR orders) ----
    const int tm = (t + 2 < 64) ? t + 2 : 63;
#pragma unroll
    for (int ms = 0; ms < 2; ms++)
#pragma unroll
      for (int r = 0; r < 4; r++)
        ld4nt(mcur[ms * 4 + r],
              mb + (q0 + ms * 16 + quad * 4 + r) * 4096 + tm * 64 + w * 16 + c);

    // ---- queue=[M(t+1):8,V(t):8,K(t+1):8,M(t+2):8]=32; vmcnt(16)
    //      retires M(t+1)+V(t). Leaves K(t+1)+M(t+2). ----
    __asm__ __volatile__("s_waitcnt vmcnt(16)"
        : "+v"(vc[0][0]), "+v"(vc[0][1]), "+v"(vc[0][2]), "+v"(vc[0][3]),
          "+v"(vc[1][0]), "+v"(vc[1][1]), "+v"(vc[1][2]), "+v"(vc[1][3]),
          "+v"(mA[0]), "+v"(mA[1]), "+v"(mA[2]), "+v"(mA[3]),
          "+v"(mA[4]), "+v"(mA[5]), "+v"(mA[6]), "+v"(mA[7]),
          "+v"(mB[0]), "+v"(mB[1]), "+v"(mB[2]), "+v"(mB[3]),
          "+v"(mB[4]), "+v"(mB[5]), "+v"(mB[6]), "+v"(mB[7]) :: "memory");

    // ---- O += P V ; row-sum via ones-frag MFMA ----
#pragma unroll
    for (int k2 = 0; k2 < 2; k2++) {
      bf8 ap[2];
#pragma unroll
      for (int ms = 0; ms < 2; ms++)  // A[m=lane&15][k=quad*8+j]
        ap[ms] = *(const bf8*)&pw[(ms * 16 + c) * 76 + k2 * 32 + quad * 8];
#pragma unroll
      for (int ms = 0; ms < 2; ms++) {
        lacc[ms] = mfma16(ap[ms], ONES, lacc[ms]);
#pragma unroll
        for (int ds = 0; ds < 4; ds++)
          accO[ms][ds] = mfma16(ap[ms], vc[k2][ds], accO[ms][ds]);
      }
    }
    // B1: K(t+1) landed in LDS; M(t+2) keeps flying; PV reads done for
    // every wave -> next tile may overwrite Plds
    __asm__ __volatile__("s_waitcnt vmcnt(8)\ns_barrier" ::: "memory");
  };

  for (int th = 0; th < 32; th++) {
    tile(2 * th, mA);
    tile(2 * th + 1, mB);
  }
  // drain in-flight tail M loads before epilogue reuses their registers
  __asm__ __volatile__("s_waitcnt vmcnt(0)" ::: "memory");

  // ---- epilogue: O / l ----
  float* ob = out + (batch * 4096 + q0) * 256;
#pragma unroll
  for (int ms = 0; ms < 2; ms++) {
    f4 rl;
#pragma unroll
    for (int r = 0; r < 4; r++) rl[r] = __builtin_amdgcn_rcpf(lacc[ms][r]);
#pragma unroll
    for (int ds = 0; ds < 4; ds++)
#pragma unroll
      for (int r = 0; r < 4; r++)
        ob[(ms * 16 + quad * 4 + r) * 256 + w * 64 + ds * 16 + c] =
            accO[ms][ds][r] * rl[r];
  }
}

extern "C" void kernel_launch(void* const* d_in, const int* in_sizes, int n_in,
                              void* d_out, int out_size, void* d_ws, size_t ws_size,
                              hipStream_t stream) {
  const float* x = (const float*)d_in[0];
  const int* mask = (const int*)d_in[1];
  const float* Wq = (const float*)d_in[2];
  const float* bq = (const float*)d_in[3];
  const float* Wk = (const float*)d_in[4];
  const float* bk = (const float*)d_in[5];
  const float* Wv = (const float*)d_in[6];
  const float* bv = (const float*)d_in[7];
  float* out = (float*)d_out;

  char* ws = (char*)d_ws;  // 24 MiB + 384 KiB
  short* Qs = (short*)ws;
  short* Kb = (short*)(ws + (8u << 20));
  short* Vt = (short*)(ws + (16u << 20));
  short* Wp = (short*)(ws + (24u << 20));

  pack<<<96, 256, 0, stream>>>(Wq, Wk, Wv, Wp);
  qkv<<<dim3(512, 3), 256, 0, stream>>>(x, Wp, bq, bk, bv, Qs, Kb, Vt);
  flash<<<512, 256, 0, stream>>>(Qs, Kb, Vt, mask, out);
}

// Round 5
// 711.395 us; speedup vs baseline: 1.7479x; 1.4216x over previous
//
#include <hip/hip_runtime.h>

// Self-attention, B=4, N=4096, D=256 (single head over full D).
//   Q = x Wq^T + bq ; K,V likewise ; S = Q K^T ; mask==0 -> -inf ;
//   attn = softmax(S/16) ; out = attn V        (fp32 in/out)
// R15: R14's cross-block atomic combine failed absmax (2.81e-3 vs 2.73e-3,
//   + a suspicious 468 un-normalized-looking absmax) -> abandoned. Same
//   occupancy lever, proven numerics instead: 16-row q-tiles, 1024 blocks,
//   each block owns its rows end-to-end (in-order fp32 accumulate +
//   in-register normalize, exactly the R12/13-passing math; deterministic,
//   no atomics, ws unchanged). Live regs ~124 (aq32+vc32+accO16+m8+lacc4)
//   fits (256,3)'s 168 budget with slack -> no spill. LDS 36.75KB.
//   3 blocks/CU = 12 waves/CU (vs 8). Cost: K/V fabric traffic 2x (~4.3GB
//   L2-side) -- deliberate discriminator vs the ~10TB/s fabric theory.
//   FIFO (steady): enter [M(t+1):4] -> +V:8 -> QK/P/B2 -> +K(t+1):8 ->
//   +M(t+2):4 = 24 -> vmcnt(12) retires M(t+1)+V -> PV -> B1 vmcnt(4)
//   retires K. Prologue drains vmcnt(0); post-loop drain for reg reuse.
// ws: Qs bf16 8MiB | Kb bf16 8MiB | Vt bf16 8MiB | Wp 384KiB

#define DEV static __device__ __forceinline__

typedef __attribute__((ext_vector_type(8))) short bf8;   // 8 bf16 (4 VGPR)
typedef __attribute__((ext_vector_type(4))) float f4;
typedef const __attribute__((address_space(1))) unsigned int* gp1;
typedef __attribute__((address_space(3))) unsigned int* lp3;

DEV short f2bf(float x) {  // fp32 -> bf16 RNE (inputs finite)
  unsigned u = __builtin_bit_cast(unsigned, x);
  u += 0x7FFFu + ((u >> 16) & 1u);
  return (short)(u >> 16);
}

DEV bf8 cvt8(f4 a, f4 b) {
  bf8 r;
  r[0] = f2bf(a[0]); r[1] = f2bf(a[1]); r[2] = f2bf(a[2]); r[3] = f2bf(a[3]);
  r[4] = f2bf(b[0]); r[5] = f2bf(b[1]); r[6] = f2bf(b[2]); r[7] = f2bf(b[3]);
  return r;
}

DEV bf8 cvtp(const float* p) { return cvt8(*(const f4*)p, *(const f4*)(p + 4)); }

DEV f4 mfma16(bf8 a, bf8 b, f4 c) {
  return __builtin_amdgcn_mfma_f32_16x16x32_bf16(a, b, c, 0, 0, 0);
}

DEV void gl_lds16(const void* g, void* l) {  // async global->LDS, 16B/lane
  __builtin_amdgcn_global_load_lds((gp1)g, (lp3)l, 16, 0, 0);
}

DEV void ld16(bf8& d, const short* p) {  // unsinkable 16B global load
  __asm__ __volatile__("global_load_dwordx4 %0, %1, off" : "=v"(d) : "v"(p));
}
DEV void ld4nt(int& d, const int* p) {   // unsinkable 4B global load, NT
  __asm__ __volatile__("global_load_dword %0, %1, off nt" : "=v"(d) : "v"(p));
}

// ---------------- kernel 0: pack W -> bf16 fragment-order (R9) ------------
__global__ void pack(const float* __restrict__ Wq, const float* __restrict__ Wk,
                     const float* __restrict__ Wv, short* __restrict__ Wp) {
  const int ch = blockIdx.x * 4 + (threadIdx.x >> 6);
  const int lane = threadIdx.x & 63;
  const int which = ch >> 7, rem = ch & 127;
  const int w = rem >> 5, e = (rem >> 3) & 3, ks = rem & 7;
  const float* W = (which == 0) ? Wq : (which == 1) ? Wk : Wv;
  bf8 v = cvtp(W + ((w * 4 + e) * 16 + (lane & 15)) * 256 + ks * 32 +
               (lane >> 4) * 8);
  *(bf8*)(Wp + ch * 512 + lane * 8) = v;
}

// ---------------- kernel 1: Q,K,V projection (R9) -------------------------
__launch_bounds__(256, 3)
__global__ void qkv(const float* __restrict__ x, const short* __restrict__ Wp,
                    const float* __restrict__ bq, const float* __restrict__ bk,
                    const float* __restrict__ bv, short* __restrict__ Qs,
                    short* __restrict__ Kb, short* __restrict__ Vt) {
  __shared__ float Xf[32 * 256];    // x tile, swizzled, 32KB
  __shared__ short Vlds[256 * 36];  // V transpose staging (which==2 only)
  const int which = blockIdx.y;
  const int m0 = blockIdx.x * 32;
  const int tid = threadIdx.x;
  const int w = tid >> 6, lane = tid & 63, quad = lane >> 4, c = lane & 15;
  const float* bias = (which == 0) ? bq : (which == 1) ? bk : bv;

#pragma unroll
  for (int l = 0; l < 8; l++) {
    const int row = l * 4 + (tid >> 6);
    const int kch = tid & 63;
    const int chg = (kch & 48) | ((kch ^ (row & 15)) & 15);  // involutive
    gl_lds16(x + (m0 + row) * 256 + chg * 4, &Xf[(l * 256 + tid) * 4]);
  }

  float bb[4];
#pragma unroll
  for (int e = 0; e < 4; e++) bb[e] = bias[(w * 4 + e) * 16 + c];

  f4 acc[2][4];
  const f4 z = {0.f, 0.f, 0.f, 0.f};
#pragma unroll
  for (int i = 0; i < 2; i++)
#pragma unroll
    for (int j = 0; j < 4; j++) acc[i][j] = z;

  __asm__ __volatile__("s_waitcnt vmcnt(0)\ns_barrier" ::: "memory");

  const short* wpb = Wp + (which * 4 + w) * 4 * 8 * 512;
#pragma unroll
  for (int ks = 0; ks < 8; ks++) {
    bf8 a[2], b[4];
#pragma unroll
    for (int ms = 0; ms < 2; ms++) {  // A[m=lane&15][k=quad*8+j]
      const int m = ms * 16 + c;
      const int ch0 = ks * 8 + quad * 2;
      const int sw0 = (ch0 & 48) | ((ch0 ^ c) & 15);
      const int sw1 = ((ch0 + 1) & 48) | (((ch0 + 1) ^ c) & 15);
      f4 f0 = *(const f4*)&Xf[m * 256 + sw0 * 4];
      f4 f1 = *(const f4*)&Xf[m * 256 + sw1 * 4];
      a[ms] = cvt8(f0, f1);
    }
#pragma unroll
    for (int e = 0; e < 4; e++)
      b[e] = *(const bf8*)(wpb + (e * 8 + ks) * 512 + lane * 8);
#pragma unroll
    for (int ms = 0; ms < 2; ms++)
#pragma unroll
      for (int e = 0; e < 4; e++) acc[ms][e] = mfma16(a[ms], b[e], acc[ms][e]);
  }

  const float sc = (which == 0) ? 0.09016844005556021f : 1.0f;  // log2e/16

  if (which < 2) {
    short* dst = (which == 0) ? Qs : Kb;
#pragma unroll
    for (int ms = 0; ms < 2; ms++)
#pragma unroll
      for (int e = 0; e < 4; e++)
#pragma unroll
        for (int r = 0; r < 4; r++)  // C/D: col=lane&15, row=quad*4+reg
          dst[(m0 + ms * 16 + quad * 4 + r) * 256 + (w * 4 + e) * 16 + c] =
              f2bf((acc[ms][e][r] + bb[e]) * sc);
  } else {
#pragma unroll
    for (int ms = 0; ms < 2; ms++)
#pragma unroll
      for (int e = 0; e < 4; e++)
#pragma unroll
        for (int r = 0; r < 4; r++)
          Vlds[((w * 4 + e) * 16 + c) * 36 + ms * 16 + quad * 4 + r] =
              f2bf(acc[ms][e][r] + bb[e]);
    __syncthreads();
    const int tt = m0 >> 6, half = m0 & 32;
#pragma unroll
    for (int j = 0; j < 4; j++) {
      int flat = j * 2048 + tid * 8;        // 256 d x 32 n
      int d = flat >> 5, n = flat & 31;
      *(bf8*)(Vt + tt * 16384 + d * 64 + half + n) =
          *(const bf8*)&Vlds[d * 36 + n];
    }
  }
}

// ---------------- kernel 2: flash attention ----------------
// 1024 WGs (3/CU). batch = bx&3, q0 = (bx>>2)*16: 16-row q-tile, block
// owns its rows end-to-end (no cross-block combine). Per tile t:
//  issue V(t) asm -> QK (Q regs, K from swizzled Klds; K(t) proven by
//  prev B1) -> P=exp2(masked S) -> B2 (lgkm0+barrier: QK reads done) ->
//  stage K(t+1) into SAME Klds -> issue M(t+2) NT -> vmcnt(12) [retires
//  M(t+1)+V(t)] -> PV -> B1 (vmcnt(4)+barrier) [K(t+1) landed].
// No compiler VM ops anywhere in the loop.
__launch_bounds__(256, 3)
__global__ void flash(const short* __restrict__ Qs, const short* __restrict__ Kb,
                      const short* __restrict__ Vt, const int* __restrict__ mask,
                      float* __restrict__ out) {
  __shared__ short Klds[16384];    // K single buf 64x256, swizzled, 32KB
  __shared__ short Plds[16 * 76];  // P 16 rows, stride 76 (conflict-free)
  const int bx = blockIdx.x;
  const int batch = bx & 3;
  const int q0 = (bx >> 2) * 16;
  const int tid = threadIdx.x;
  const int w = tid >> 6, lane = tid & 63, quad = lane >> 4, c = lane & 15;

  const short* kb = Kb + batch * 4096 * 256;
  const short* vb = Vt + batch * 1048576;
  const int* mb = mask + batch * 16777216;

  const int krow = tid >> 5;  // K staging: row-in-8-row-line (0..7)
  const int kch = tid & 31;   // LDS chunk this thread fills

  // ---- prologue: K(0)->Klds, M(0)->mA, M(1)->mB, Q via asm ----
#pragma unroll
  for (int l = 0; l < 8; l++) {
    const int row = l * 8 + krow;
    const int chg = (kch & 16) | ((kch ^ row) & 15);  // involutive swizzle
    gl_lds16(kb + row * 256 + chg * 8, &Klds[l * 2048 + tid * 8]);
  }
  int mA[4], mB[4];
#pragma unroll
  for (int r = 0; r < 4; r++) {
    ld4nt(mA[r], mb + (q0 + quad * 4 + r) * 4096 + w * 16 + c);
    ld4nt(mB[r], mb + (q0 + quad * 4 + r) * 4096 + 64 + w * 16 + c);
  }
  bf8 aq[8];
  const short* qb = Qs + (batch * 4096 + q0) * 256;
#pragma unroll
  for (int ks = 0; ks < 8; ks++)
    ld16(aq[ks], qb + c * 256 + ks * 32 + quad * 8);

  const f4 z = {0.f, 0.f, 0.f, 0.f};
  f4 accO[4], lacc = z;
#pragma unroll
  for (int ds = 0; ds < 4; ds++) accO[ds] = z;
  const bf8 ONES = {0x3F80, 0x3F80, 0x3F80, 0x3F80, 0x3F80, 0x3F80, 0x3F80, 0x3F80};

  // drain prologue; tie aq (8) + mA (4) + mB (4) = 16 operands
  __asm__ __volatile__("s_waitcnt vmcnt(0)\ns_barrier"
      : "+v"(aq[0]), "+v"(aq[1]), "+v"(aq[2]), "+v"(aq[3]),
        "+v"(aq[4]), "+v"(aq[5]), "+v"(aq[6]), "+v"(aq[7]),
        "+v"(mA[0]), "+v"(mA[1]), "+v"(mA[2]), "+v"(mA[3]),
        "+v"(mB[0]), "+v"(mB[1]), "+v"(mB[2]), "+v"(mB[3]) :: "memory");

  auto tile = [&](int t, int* mcur) {
    // ---- issue V(t) (asm regs) ----
    bf8 vc[2][4];
#pragma unroll
    for (int k2 = 0; k2 < 2; k2++)
#pragma unroll
      for (int ds = 0; ds < 4; ds++)
        ld16(vc[k2][ds], vb + t * 16384 + (w * 64 + ds * 16 + c) * 64 +
                         k2 * 32 + quad * 8);

    // ---- S = Q' K^T from swizzled Klds (K(t) proven by prev B1) ----
    f4 s = z;
#pragma unroll
    for (int ks = 0; ks < 8; ks++) {
      const int ch = ks * 4 + quad;
      const int sw = (ch & 16) | ((ch ^ c) & 15);
      const bf8 kf = *(const bf8*)&Klds[(w * 16 + c) * 256 + sw * 8];
      s = mfma16(aq[ks], kf, s);
    }

    // ---- P = exp2(masked S) -> Plds (mask regs retired by prev vmcnt12) --
    short* pw = &Plds[0];
#pragma unroll
    for (int r = 0; r < 4; r++) {
      float sv = (mcur[r] != 0) ? s[r] : -INFINITY;
      pw[(quad * 4 + r) * 76 + w * 16 + c] = f2bf(__builtin_amdgcn_exp2f(sv));
    }
    // B2: P visible; all QK reads of K(t) complete across the block
    __asm__ __volatile__("s_waitcnt lgkmcnt(0)\ns_barrier" ::: "memory");

    // ---- stage K(t+1) into the SAME buffer (safe past B2) ----
    const int tk = (t < 63) ? t + 1 : 63;
    const short* kbt = kb + tk * 16384;
#pragma unroll
    for (int l = 0; l < 8; l++) {
      const int row = l * 8 + krow;
      const int chg = (kch & 16) | ((kch ^ row) & 15);
      gl_lds16(kbt + row * 256 + chg * 8, &Klds[l * 2048 + tid * 8]);
    }

    // ---- issue M(t+2) into mcur (P reads above done; reg WAR orders) ----
    const int tm = (t + 2 < 64) ? t + 2 : 63;
#pragma unroll
    for (int r = 0; r < 4; r++)
      ld4nt(mcur[r], mb + (q0 + quad * 4 + r) * 4096 + tm * 64 + w * 16 + c);

    // ---- queue=[M(t+1):4,V(t):8,K(t+1):8,M(t+2):4]=24; vmcnt(12)
    //      retires M(t+1)+V(t). Leaves K(t+1)+M(t+2). ----
    __asm__ __volatile__("s_waitcnt vmcnt(12)"
        : "+v"(vc[0][0]), "+v"(vc[0][1]), "+v"(vc[0][2]), "+v"(vc[0][3]),
          "+v"(vc[1][0]), "+v"(vc[1][1]), "+v"(vc[1][2]), "+v"(vc[1][3]),
          "+v"(mA[0]), "+v"(mA[1]), "+v"(mA[2]), "+v"(mA[3]),
          "+v"(mB[0]), "+v"(mB[1]), "+v"(mB[2]), "+v"(mB[3]) :: "memory");

    // ---- O += P V ; row-sum via ones-frag MFMA ----
#pragma unroll
    for (int k2 = 0; k2 < 2; k2++) {
      // A[m=lane&15][k=quad*8+j]
      const bf8 ap = *(const bf8*)&pw[c * 76 + k2 * 32 + quad * 8];
      lacc = mfma16(ap, ONES, lacc);
#pragma unroll
      for (int ds = 0; ds < 4; ds++)
        accO[ds] = mfma16(ap, vc[k2][ds], accO[ds]);
    }
    // B1: K(t+1) landed in LDS; M(t+2) keeps flying; PV reads done for
    // every wave -> next tile may overwrite Plds
    __asm__ __volatile__("s_waitcnt vmcnt(4)\ns_barrier" ::: "memory");
  };

  for (int th = 0; th < 32; th++) {
    tile(2 * th, mA);
    tile(2 * th + 1, mB);
  }
  // drain in-flight tail M loads before epilogue reuses their registers
  __asm__ __volatile__("s_waitcnt vmcnt(0)" ::: "memory");

  // ---- epilogue: O / l (in-register, deterministic) ----
  float* ob = out + (batch * 4096 + q0) * 256;
  f4 rl;
#pragma unroll
  for (int r = 0; r < 4; r++) rl[r] = __builtin_amdgcn_rcpf(lacc[r]);
#pragma unroll
  for (int ds = 0; ds < 4; ds++)
#pragma unroll
    for (int r = 0; r < 4; r++)
      ob[(quad * 4 + r) * 256 + w * 64 + ds * 16 + c] = accO[ds][r] * rl[r];
}

extern "C" void kernel_launch(void* const* d_in, const int* in_sizes, int n_in,
                              void* d_out, int out_size, void* d_ws, size_t ws_size,
                              hipStream_t stream) {
  const float* x = (const float*)d_in[0];
  const int* mask = (const int*)d_in[1];
  const float* Wq = (const float*)d_in[2];
  const float* bq = (const float*)d_in[3];
  const float* Wk = (const float*)d_in[4];
  const float* bk = (const float*)d_in[5];
  const float* Wv = (const float*)d_in[6];
  const float* bv = (const float*)d_in[7];
  float* out = (float*)d_out;

  char* ws = (char*)d_ws;  // 24 MiB + 384 KiB
  short* Qs = (short*)ws;
  short* Kb = (short*)(ws + (8u << 20));
  short* Vt = (short*)(ws + (16u << 20));
  short* Wp = (short*)(ws + (24u << 20));

  pack<<<96, 256, 0, stream>>>(Wq, Wk, Wv, Wp);
  qkv<<<dim3(512, 3), 256, 0, stream>>>(x, Wp, bq, bk, bv, Qs, Kb, Vt);
  flash<<<1024, 256, 0, stream>>>(Qs, Kb, Vt, mask, out);
}

// Round 6
// 581.059 us; speedup vs baseline: 2.1399x; 1.2243x over previous
//
#include <hip/hip_runtime.h>

// Self-attention, B=4, N=4096, D=256 (single head over full D).
//   Q = x Wq^T + bq ; K,V likewise ; S = Q K^T ; mask==0 -> -inf ;
//   attn = softmax(S/16) ; out = attn V        (fp32 in/out)
// R16: BW-wall identified. R0/R1/R15 all plateau at 10.5+-0.5 TB/s of
//   L2-side traffic (2.36GB/234us, 2.36/224, 4.46/400 -- R15's time is
//   predicted within 6% by constant-BW scaling). Occupancy moves (2->3
//   blocks/CU) change nothing; traffic moves change time proportionally.
//   Lever: bytes/output. 64-row q-tiles halve K/V re-reads: 256 blocks x
//   512 threads (8 waves: h=w8>>2 picks 32-row half, wc=w8&3 picks 64-col
//   slice). Traffic 1.31GB (0.55x R0) -> predict flash ~125us.
//   Q in registers per wave (aq 64 VGPR; (512,2) budget 256, no spill).
//   V loads duplicated by h=0/h=1 wave pairs -> same lines, L1/MSHR
//   absorbs. LDS = K 32KB + P 9.5KB = 41.5KB. Deterministic per-block
//   math identical to R0 (passing absmax 4.88e-4).
//   FIFO/thread (K stage = 4 gl_lds): steady [M(t+1):8] +V:8 -> QK/P/B2
//   -> +K(t+1):4 +M(t+2):8 = 28 -> vmcnt(12) retires M(t+1)+V -> PV ->
//   B1 vmcnt(8) retires K (leaves M(t+2):8). Prologue vmcnt(0); post-loop
//   drain before epilogue.
// ws: Qs bf16 8MiB | Kb bf16 8MiB | Vt bf16 8MiB | Wp 384KiB

#define DEV static __device__ __forceinline__

typedef __attribute__((ext_vector_type(8))) short bf8;   // 8 bf16 (4 VGPR)
typedef __attribute__((ext_vector_type(4))) float f4;
typedef const __attribute__((address_space(1))) unsigned int* gp1;
typedef __attribute__((address_space(3))) unsigned int* lp3;

DEV short f2bf(float x) {  // fp32 -> bf16 RNE (inputs finite)
  unsigned u = __builtin_bit_cast(unsigned, x);
  u += 0x7FFFu + ((u >> 16) & 1u);
  return (short)(u >> 16);
}

DEV bf8 cvt8(f4 a, f4 b) {
  bf8 r;
  r[0] = f2bf(a[0]); r[1] = f2bf(a[1]); r[2] = f2bf(a[2]); r[3] = f2bf(a[3]);
  r[4] = f2bf(b[0]); r[5] = f2bf(b[1]); r[6] = f2bf(b[2]); r[7] = f2bf(b[3]);
  return r;
}

DEV bf8 cvtp(const float* p) { return cvt8(*(const f4*)p, *(const f4*)(p + 4)); }

DEV f4 mfma16(bf8 a, bf8 b, f4 c) {
  return __builtin_amdgcn_mfma_f32_16x16x32_bf16(a, b, c, 0, 0, 0);
}

DEV void gl_lds16(const void* g, void* l) {  // async global->LDS, 16B/lane
  __builtin_amdgcn_global_load_lds((gp1)g, (lp3)l, 16, 0, 0);
}

DEV void ld16(bf8& d, const short* p) {  // unsinkable 16B global load
  __asm__ __volatile__("global_load_dwordx4 %0, %1, off" : "=v"(d) : "v"(p));
}
DEV void ld4nt(int& d, const int* p) {   // unsinkable 4B global load, NT
  __asm__ __volatile__("global_load_dword %0, %1, off nt" : "=v"(d) : "v"(p));
}

// ---------------- kernel 0: pack W -> bf16 fragment-order (R9) ------------
__global__ void pack(const float* __restrict__ Wq, const float* __restrict__ Wk,
                     const float* __restrict__ Wv, short* __restrict__ Wp) {
  const int ch = blockIdx.x * 4 + (threadIdx.x >> 6);
  const int lane = threadIdx.x & 63;
  const int which = ch >> 7, rem = ch & 127;
  const int w = rem >> 5, e = (rem >> 3) & 3, ks = rem & 7;
  const float* W = (which == 0) ? Wq : (which == 1) ? Wk : Wv;
  bf8 v = cvtp(W + ((w * 4 + e) * 16 + (lane & 15)) * 256 + ks * 32 +
               (lane >> 4) * 8);
  *(bf8*)(Wp + ch * 512 + lane * 8) = v;
}

// ---------------- kernel 1: Q,K,V projection (R9) -------------------------
__launch_bounds__(256, 3)
__global__ void qkv(const float* __restrict__ x, const short* __restrict__ Wp,
                    const float* __restrict__ bq, const float* __restrict__ bk,
                    const float* __restrict__ bv, short* __restrict__ Qs,
                    short* __restrict__ Kb, short* __restrict__ Vt) {
  __shared__ float Xf[32 * 256];    // x tile, swizzled, 32KB
  __shared__ short Vlds[256 * 36];  // V transpose staging (which==2 only)
  const int which = blockIdx.y;
  const int m0 = blockIdx.x * 32;
  const int tid = threadIdx.x;
  const int w = tid >> 6, lane = tid & 63, quad = lane >> 4, c = lane & 15;
  const float* bias = (which == 0) ? bq : (which == 1) ? bk : bv;

#pragma unroll
  for (int l = 0; l < 8; l++) {
    const int row = l * 4 + (tid >> 6);
    const int kch = tid & 63;
    const int chg = (kch & 48) | ((kch ^ (row & 15)) & 15);  // involutive
    gl_lds16(x + (m0 + row) * 256 + chg * 4, &Xf[(l * 256 + tid) * 4]);
  }

  float bb[4];
#pragma unroll
  for (int e = 0; e < 4; e++) bb[e] = bias[(w * 4 + e) * 16 + c];

  f4 acc[2][4];
  const f4 z = {0.f, 0.f, 0.f, 0.f};
#pragma unroll
  for (int i = 0; i < 2; i++)
#pragma unroll
    for (int j = 0; j < 4; j++) acc[i][j] = z;

  __asm__ __volatile__("s_waitcnt vmcnt(0)\ns_barrier" ::: "memory");

  const short* wpb = Wp + (which * 4 + w) * 4 * 8 * 512;
#pragma unroll
  for (int ks = 0; ks < 8; ks++) {
    bf8 a[2], b[4];
#pragma unroll
    for (int ms = 0; ms < 2; ms++) {  // A[m=lane&15][k=quad*8+j]
      const int m = ms * 16 + c;
      const int ch0 = ks * 8 + quad * 2;
      const int sw0 = (ch0 & 48) | ((ch0 ^ c) & 15);
      const int sw1 = ((ch0 + 1) & 48) | (((ch0 + 1) ^ c) & 15);
      f4 f0 = *(const f4*)&Xf[m * 256 + sw0 * 4];
      f4 f1 = *(const f4*)&Xf[m * 256 + sw1 * 4];
      a[ms] = cvt8(f0, f1);
    }
#pragma unroll
    for (int e = 0; e < 4; e++)
      b[e] = *(const bf8*)(wpb + (e * 8 + ks) * 512 + lane * 8);
#pragma unroll
    for (int ms = 0; ms < 2; ms++)
#pragma unroll
      for (int e = 0; e < 4; e++) acc[ms][e] = mfma16(a[ms], b[e], acc[ms][e]);
  }

  const float sc = (which == 0) ? 0.09016844005556021f : 1.0f;  // log2e/16

  if (which < 2) {
    short* dst = (which == 0) ? Qs : Kb;
#pragma unroll
    for (int ms = 0; ms < 2; ms++)
#pragma unroll
      for (int e = 0; e < 4; e++)
#pragma unroll
        for (int r = 0; r < 4; r++)  // C/D: col=lane&15, row=quad*4+reg
          dst[(m0 + ms * 16 + quad * 4 + r) * 256 + (w * 4 + e) * 16 + c] =
              f2bf((acc[ms][e][r] + bb[e]) * sc);
  } else {
#pragma unroll
    for (int ms = 0; ms < 2; ms++)
#pragma unroll
      for (int e = 0; e < 4; e++)
#pragma unroll
        for (int r = 0; r < 4; r++)
          Vlds[((w * 4 + e) * 16 + c) * 36 + ms * 16 + quad * 4 + r] =
              f2bf(acc[ms][e][r] + bb[e]);
    __syncthreads();
    const int tt = m0 >> 6, half = m0 & 32;
#pragma unroll
    for (int j = 0; j < 4; j++) {
      int flat = j * 2048 + tid * 8;        // 256 d x 32 n
      int d = flat >> 5, n = flat & 31;
      *(bf8*)(Vt + tt * 16384 + d * 64 + half + n) =
          *(const bf8*)&Vlds[d * 36 + n];
    }
  }
}

// ---------------- kernel 2: flash attention ----------------
// 256 WGs x 512 threads (8 waves, 1 block/CU). batch = bx&3, q0 =
// (bx>>2)*64. Wave w8: h = w8>>2 (q-rows h*32..+31), wc = w8&3 (cols
// wc*64..+63 for PV/out, k-cols wc*16..+15 for QK/P). Per tile t:
//  issue V(t) asm -> QK (Q regs, K from swizzled Klds) -> P=exp2(masked)
//  -> B2 (lgkm0+barrier) -> stage K(t+1) same buf (4 gl_lds) -> issue
//  M(t+2) NT -> vmcnt(12) [retires M(t+1)+V(t)] -> PV -> B1 (vmcnt(8)
//  +barrier) [K(t+1) landed; M(t+2) flies]. No compiler VM ops in loop.
__launch_bounds__(512, 2)
__global__ void flash(const short* __restrict__ Qs, const short* __restrict__ Kb,
                      const short* __restrict__ Vt, const int* __restrict__ mask,
                      float* __restrict__ out) {
  __shared__ short Klds[16384];    // K single buf 64x256, swizzled, 32KB
  __shared__ short Plds[64 * 76];  // P 64 rows, stride 76 (conflict-free)
  const int bx = blockIdx.x;
  const int batch = bx & 3;
  const int q0 = (bx >> 2) * 64;
  const int tid = threadIdx.x;
  const int lane = tid & 63, quad = lane >> 4, c = lane & 15;
  const int w8 = tid >> 6, h = w8 >> 2, wc = w8 & 3;

  const short* kb = Kb + batch * 4096 * 256;
  const short* vb = Vt + batch * 1048576;
  const int* mb = mask + batch * 16777216;

  const int krow = tid >> 5;  // K staging row-in-16-row-line (0..15)
  const int kch = tid & 31;   // LDS chunk this thread fills

  // ---- prologue: K(0)->Klds, M(0)->mA, M(1)->mB, Q via asm ----
#pragma unroll
  for (int l = 0; l < 4; l++) {
    const int row = l * 16 + krow;
    const int chg = (kch & 16) | ((kch ^ row) & 15);  // involutive swizzle
    gl_lds16(kb + row * 256 + chg * 8, &Klds[l * 4096 + tid * 8]);
  }
  int mA[8], mB[8];
#pragma unroll
  for (int ms = 0; ms < 2; ms++)
#pragma unroll
    for (int r = 0; r < 4; r++) {
      const int qr = q0 + h * 32 + ms * 16 + quad * 4 + r;
      ld4nt(mA[ms * 4 + r], mb + qr * 4096 + wc * 16 + c);
      ld4nt(mB[ms * 4 + r], mb + qr * 4096 + 64 + wc * 16 + c);
    }
  bf8 aq[2][8];
  const short* qb = Qs + (batch * 4096 + q0) * 256;
#pragma unroll
  for (int ms = 0; ms < 2; ms++)
#pragma unroll
    for (int ks = 0; ks < 8; ks++)
      ld16(aq[ms][ks], qb + (h * 32 + ms * 16 + c) * 256 + ks * 32 + quad * 8);

  const f4 z = {0.f, 0.f, 0.f, 0.f};
  f4 accO[2][4], lacc[2];
#pragma unroll
  for (int ms = 0; ms < 2; ms++) {
    lacc[ms] = z;
#pragma unroll
    for (int ds = 0; ds < 4; ds++) accO[ms][ds] = z;
  }
  const bf8 ONES = {0x3F80, 0x3F80, 0x3F80, 0x3F80, 0x3F80, 0x3F80, 0x3F80, 0x3F80};

  // drain prologue; tie aq on the waitcnt, masks on a follow-up tie asm
  __asm__ __volatile__("s_waitcnt vmcnt(0)\ns_barrier"
      : "+v"(aq[0][0]), "+v"(aq[0][1]), "+v"(aq[0][2]), "+v"(aq[0][3]),
        "+v"(aq[0][4]), "+v"(aq[0][5]), "+v"(aq[0][6]), "+v"(aq[0][7]),
        "+v"(aq[1][0]), "+v"(aq[1][1]), "+v"(aq[1][2]), "+v"(aq[1][3]),
        "+v"(aq[1][4]), "+v"(aq[1][5]), "+v"(aq[1][6]), "+v"(aq[1][7])
      :: "memory");
  __asm__ __volatile__(""
      : "+v"(mA[0]), "+v"(mA[1]), "+v"(mA[2]), "+v"(mA[3]),
        "+v"(mA[4]), "+v"(mA[5]), "+v"(mA[6]), "+v"(mA[7]),
        "+v"(mB[0]), "+v"(mB[1]), "+v"(mB[2]), "+v"(mB[3]),
        "+v"(mB[4]), "+v"(mB[5]), "+v"(mB[6]), "+v"(mB[7]) :: "memory");

  auto tile = [&](int t, int* mcur) {
    // ---- issue V(t) (asm regs); h=0/h=1 wave pairs share lines (L1) ----
    bf8 vc[2][4];
#pragma unroll
    for (int k2 = 0; k2 < 2; k2++)
#pragma unroll
      for (int ds = 0; ds < 4; ds++)
        ld16(vc[k2][ds], vb + t * 16384 + (wc * 64 + ds * 16 + c) * 64 +
                         k2 * 32 + quad * 8);

    // ---- S = Q' K^T from swizzled Klds (K(t) proven by prev B1) ----
    f4 s[2];
#pragma unroll
    for (int ms = 0; ms < 2; ms++) s[ms] = z;
#pragma unroll
    for (int ks = 0; ks < 8; ks++) {
      const int ch = ks * 4 + quad;
      const int sw = (ch & 16) | ((ch ^ c) & 15);
      const bf8 kf = *(const bf8*)&Klds[(wc * 16 + c) * 256 + sw * 8];
#pragma unroll
      for (int ms = 0; ms < 2; ms++) s[ms] = mfma16(aq[ms][ks], kf, s[ms]);
    }

    // ---- P = exp2(masked S) -> Plds (mask regs retired by prev vmcnt12) --
    short* pw = &Plds[0];
#pragma unroll
    for (int ms = 0; ms < 2; ms++)
#pragma unroll
      for (int r = 0; r < 4; r++) {
        float sv = (mcur[ms * 4 + r] != 0) ? s[ms][r] : -INFINITY;
        pw[(h * 32 + ms * 16 + quad * 4 + r) * 76 + wc * 16 + c] =
            f2bf(__builtin_amdgcn_exp2f(sv));
      }
    // B2: P visible; all QK reads of K(t) complete across the block
    __asm__ __volatile__("s_waitcnt lgkmcnt(0)\ns_barrier" ::: "memory");

    // ---- stage K(t+1) into the SAME buffer (safe past B2) ----
    const int tk = (t < 63) ? t + 1 : 63;
    const short* kbt = kb + tk * 16384;
#pragma unroll
    for (int l = 0; l < 4; l++) {
      const int row = l * 16 + krow;
      const int chg = (kch & 16) | ((kch ^ row) & 15);
      gl_lds16(kbt + row * 256 + chg * 8, &Klds[l * 4096 + tid * 8]);
    }

    // ---- issue M(t+2) into mcur (P reads above done; reg WAR orders) ----
    const int tm = (t + 2 < 64) ? t + 2 : 63;
#pragma unroll
    for (int ms = 0; ms < 2; ms++)
#pragma unroll
      for (int r = 0; r < 4; r++)
        ld4nt(mcur[ms * 4 + r],
              mb + (q0 + h * 32 + ms * 16 + quad * 4 + r) * 4096 + tm * 64 +
                  wc * 16 + c);

    // ---- queue=[M(t+1):8,V(t):8,K(t+1):4,M(t+2):8]=28; vmcnt(12)
    //      retires M(t+1)+V(t). Leaves K4+M8=12. ----
    __asm__ __volatile__("s_waitcnt vmcnt(12)"
        : "+v"(vc[0][0]), "+v"(vc[0][1]), "+v"(vc[0][2]), "+v"(vc[0][3]),
          "+v"(vc[1][0]), "+v"(vc[1][1]), "+v"(vc[1][2]), "+v"(vc[1][3]),
          "+v"(mA[0]), "+v"(mA[1]), "+v"(mA[2]), "+v"(mA[3]),
          "+v"(mA[4]), "+v"(mA[5]), "+v"(mA[6]), "+v"(mA[7]),
          "+v"(mB[0]), "+v"(mB[1]), "+v"(mB[2]), "+v"(mB[3]),
          "+v"(mB[4]), "+v"(mB[5]), "+v"(mB[6]), "+v"(mB[7]) :: "memory");

    // ---- O += P V ; row-sum via ones-frag MFMA ----
#pragma unroll
    for (int k2 = 0; k2 < 2; k2++) {
      bf8 ap[2];
#pragma unroll
      for (int ms = 0; ms < 2; ms++)  // A[m=lane&15][k=quad*8+j]
        ap[ms] = *(const bf8*)&pw[(h * 32 + ms * 16 + c) * 76 + k2 * 32 +
                                  quad * 8];
#pragma unroll
      for (int ms = 0; ms < 2; ms++) {
        lacc[ms] = mfma16(ap[ms], ONES, lacc[ms]);
#pragma unroll
        for (int ds = 0; ds < 4; ds++)
          accO[ms][ds] = mfma16(ap[ms], vc[k2][ds], accO[ms][ds]);
      }
    }
    // B1: K(t+1) landed in LDS (vmcnt 12->8 retires the 4 K chunks);
    // M(t+2) keeps flying; PV reads done -> next tile may overwrite Plds
    __asm__ __volatile__("s_waitcnt vmcnt(8)\ns_barrier" ::: "memory");
  };

  for (int th = 0; th < 32; th++) {
    tile(2 * th, mA);
    tile(2 * th + 1, mB);
  }
  // drain in-flight tail M loads before epilogue reuses their registers
  __asm__ __volatile__("s_waitcnt vmcnt(0)" ::: "memory");

  // ---- epilogue: O / l (in-register, deterministic) ----
  float* ob = out + (batch * 4096 + q0) * 256;
#pragma unroll
  for (int ms = 0; ms < 2; ms++) {
    f4 rl;
#pragma unroll
    for (int r = 0; r < 4; r++) rl[r] = __builtin_amdgcn_rcpf(lacc[ms][r]);
#pragma unroll
    for (int ds = 0; ds < 4; ds++)
#pragma unroll
      for (int r = 0; r < 4; r++)
        ob[(h * 32 + ms * 16 + quad * 4 + r) * 256 + wc * 64 + ds * 16 + c] =
            accO[ms][ds][r] * rl[r];
  }
}

extern "C" void kernel_launch(void* const* d_in, const int* in_sizes, int n_in,
                              void* d_out, int out_size, void* d_ws, size_t ws_size,
                              hipStream_t stream) {
  const float* x = (const float*)d_in[0];
  const int* mask = (const int*)d_in[1];
  const float* Wq = (const float*)d_in[2];
  const float* bq = (const float*)d_in[3];
  const float* Wk = (const float*)d_in[4];
  const float* bk = (const float*)d_in[5];
  const float* Wv = (const float*)d_in[6];
  const float* bv = (const float*)d_in[7];
  float* out = (float*)d_out;

  char* ws = (char*)d_ws;  // 24 MiB + 384 KiB
  short* Qs = (short*)ws;
  short* Kb = (short*)(ws + (8u << 20));
  short* Vt = (short*)(ws + (16u << 20));
  short* Wp = (short*)(ws + (24u << 20));

  pack<<<96, 256, 0, stream>>>(Wq, Wk, Wv, Wp);
  qkv<<<dim3(512, 3), 256, 0, stream>>>(x, Wp, bq, bk, bv, Qs, Kb, Vt);
  flash<<<256, 512, 0, stream>>>(Qs, Kb, Vt, mask, out);
}

// Round 7
// 499.089 us; speedup vs baseline: 2.4914x; 1.1642x over previous
//
#include <hip/hip_runtime.h>

// Self-attention, B=4, N=4096, D=256 (single head over full D).
//   Q = x Wq^T + bq ; K,V likewise ; S = Q K^T ; mask==0 -> -inf ;
//   attn = softmax(S/16) ; out = attn V        (fp32 in/out)
// R17: unified bottleneck found: VMEM LINE-REQUESTS, not bytes/latency.
//   V reg-loads are 128B-strided 16B/lane -> 64 lines/instr. Counting V
//   requests/CU: R0 262k/234us, R16 262k/266us, R15 524k/400us -- all
//   ~0.5 line-req/cy/CU. Fix: V staged through LDS via coalesced
//   gl_lds16 (8 lines/instr) into swizzled [256 d][64 k] buffer
//   (chunk ^= d&7, involutive; same proven pattern as K). PV reads
//   ds_read_b128, conflict-free. Requests/block-tile 4600 -> ~770.
//   Pipeline: A stage V(t) -> QK -> P -> B2(lgkm0+bar) -> stage K(t+1)
//   -> M(t+2) NT -> E vmcnt(12)+bar [V landed block-wide; retires
//   M(t+1)] -> PV (V,P from LDS) -> B1 vmcnt(8)+bar [K landed].
//   FIFO steady: [M8]+V4+K4+M8=24 -> vmcnt(12) -> PV -> vmcnt(8).
//   vc regs gone (-32 VGPR); (512,1) -> no scratch. LDS 73.5KB, 1 blk/CU.
// ws: Qs bf16 8MiB | Kb bf16 8MiB | Vt bf16 8MiB | Wp 384KiB

#define DEV static __device__ __forceinline__

typedef __attribute__((ext_vector_type(8))) short bf8;   // 8 bf16 (4 VGPR)
typedef __attribute__((ext_vector_type(4))) float f4;
typedef const __attribute__((address_space(1))) unsigned int* gp1;
typedef __attribute__((address_space(3))) unsigned int* lp3;

DEV short f2bf(float x) {  // fp32 -> bf16 RNE (inputs finite)
  unsigned u = __builtin_bit_cast(unsigned, x);
  u += 0x7FFFu + ((u >> 16) & 1u);
  return (short)(u >> 16);
}

DEV bf8 cvt8(f4 a, f4 b) {
  bf8 r;
  r[0] = f2bf(a[0]); r[1] = f2bf(a[1]); r[2] = f2bf(a[2]); r[3] = f2bf(a[3]);
  r[4] = f2bf(b[0]); r[5] = f2bf(b[1]); r[6] = f2bf(b[2]); r[7] = f2bf(b[3]);
  return r;
}

DEV bf8 cvtp(const float* p) { return cvt8(*(const f4*)p, *(const f4*)(p + 4)); }

DEV f4 mfma16(bf8 a, bf8 b, f4 c) {
  return __builtin_amdgcn_mfma_f32_16x16x32_bf16(a, b, c, 0, 0, 0);
}

DEV void gl_lds16(const void* g, void* l) {  // async global->LDS, 16B/lane
  __builtin_amdgcn_global_load_lds((gp1)g, (lp3)l, 16, 0, 0);
}

DEV void ld16(bf8& d, const short* p) {  // unsinkable 16B global load
  __asm__ __volatile__("global_load_dwordx4 %0, %1, off" : "=v"(d) : "v"(p));
}
DEV void ld4nt(int& d, const int* p) {   // unsinkable 4B global load, NT
  __asm__ __volatile__("global_load_dword %0, %1, off nt" : "=v"(d) : "v"(p));
}

// ---------------- kernel 0: pack W -> bf16 fragment-order (R9) ------------
__global__ void pack(const float* __restrict__ Wq, const float* __restrict__ Wk,
                     const float* __restrict__ Wv, short* __restrict__ Wp) {
  const int ch = blockIdx.x * 4 + (threadIdx.x >> 6);
  const int lane = threadIdx.x & 63;
  const int which = ch >> 7, rem = ch & 127;
  const int w = rem >> 5, e = (rem >> 3) & 3, ks = rem & 7;
  const float* W = (which == 0) ? Wq : (which == 1) ? Wk : Wv;
  bf8 v = cvtp(W + ((w * 4 + e) * 16 + (lane & 15)) * 256 + ks * 32 +
               (lane >> 4) * 8);
  *(bf8*)(Wp + ch * 512 + lane * 8) = v;
}

// ---------------- kernel 1: Q,K,V projection (R9) -------------------------
__launch_bounds__(256, 3)
__global__ void qkv(const float* __restrict__ x, const short* __restrict__ Wp,
                    const float* __restrict__ bq, const float* __restrict__ bk,
                    const float* __restrict__ bv, short* __restrict__ Qs,
                    short* __restrict__ Kb, short* __restrict__ Vt) {
  __shared__ float Xf[32 * 256];    // x tile, swizzled, 32KB
  __shared__ short Vlds[256 * 36];  // V transpose staging (which==2 only)
  const int which = blockIdx.y;
  const int m0 = blockIdx.x * 32;
  const int tid = threadIdx.x;
  const int w = tid >> 6, lane = tid & 63, quad = lane >> 4, c = lane & 15;
  const float* bias = (which == 0) ? bq : (which == 1) ? bk : bv;

#pragma unroll
  for (int l = 0; l < 8; l++) {
    const int row = l * 4 + (tid >> 6);
    const int kch = tid & 63;
    const int chg = (kch & 48) | ((kch ^ (row & 15)) & 15);  // involutive
    gl_lds16(x + (m0 + row) * 256 + chg * 4, &Xf[(l * 256 + tid) * 4]);
  }

  float bb[4];
#pragma unroll
  for (int e = 0; e < 4; e++) bb[e] = bias[(w * 4 + e) * 16 + c];

  f4 acc[2][4];
  const f4 z = {0.f, 0.f, 0.f, 0.f};
#pragma unroll
  for (int i = 0; i < 2; i++)
#pragma unroll
    for (int j = 0; j < 4; j++) acc[i][j] = z;

  __asm__ __volatile__("s_waitcnt vmcnt(0)\ns_barrier" ::: "memory");

  const short* wpb = Wp + (which * 4 + w) * 4 * 8 * 512;
#pragma unroll
  for (int ks = 0; ks < 8; ks++) {
    bf8 a[2], b[4];
#pragma unroll
    for (int ms = 0; ms < 2; ms++) {  // A[m=lane&15][k=quad*8+j]
      const int m = ms * 16 + c;
      const int ch0 = ks * 8 + quad * 2;
      const int sw0 = (ch0 & 48) | ((ch0 ^ c) & 15);
      const int sw1 = ((ch0 + 1) & 48) | (((ch0 + 1) ^ c) & 15);
      f4 f0 = *(const f4*)&Xf[m * 256 + sw0 * 4];
      f4 f1 = *(const f4*)&Xf[m * 256 + sw1 * 4];
      a[ms] = cvt8(f0, f1);
    }
#pragma unroll
    for (int e = 0; e < 4; e++)
      b[e] = *(const bf8*)(wpb + (e * 8 + ks) * 512 + lane * 8);
#pragma unroll
    for (int ms = 0; ms < 2; ms++)
#pragma unroll
      for (int e = 0; e < 4; e++) acc[ms][e] = mfma16(a[ms], b[e], acc[ms][e]);
  }

  const float sc = (which == 0) ? 0.09016844005556021f : 1.0f;  // log2e/16

  if (which < 2) {
    short* dst = (which == 0) ? Qs : Kb;
#pragma unroll
    for (int ms = 0; ms < 2; ms++)
#pragma unroll
      for (int e = 0; e < 4; e++)
#pragma unroll
        for (int r = 0; r < 4; r++)  // C/D: col=lane&15, row=quad*4+reg
          dst[(m0 + ms * 16 + quad * 4 + r) * 256 + (w * 4 + e) * 16 + c] =
              f2bf((acc[ms][e][r] + bb[e]) * sc);
  } else {
#pragma unroll
    for (int ms = 0; ms < 2; ms++)
#pragma unroll
      for (int e = 0; e < 4; e++)
#pragma unroll
        for (int r = 0; r < 4; r++)
          Vlds[((w * 4 + e) * 16 + c) * 36 + ms * 16 + quad * 4 + r] =
              f2bf(acc[ms][e][r] + bb[e]);
    __syncthreads();
    const int tt = m0 >> 6, half = m0 & 32;
#pragma unroll
    for (int j = 0; j < 4; j++) {
      int flat = j * 2048 + tid * 8;        // 256 d x 32 n
      int d = flat >> 5, n = flat & 31;
      *(bf8*)(Vt + tt * 16384 + d * 64 + half + n) =
          *(const bf8*)&Vlds[d * 36 + n];
    }
  }
}

// ---------------- kernel 2: flash attention ----------------
// 256 WGs x 512 threads (8 waves, 1 block/CU). batch = bx&3, q0 =
// (bx>>2)*64. Wave w8: h = w8>>2 (q-rows h*32..+31), wc = w8&3 (cols
// wc*64..+63 for PV/out, k-cols wc*16..+15 for QK/P). All K and V
// traffic via coalesced gl_lds16; NO strided register VM loads.
__launch_bounds__(512, 1)
__global__ void flash(const short* __restrict__ Qs, const short* __restrict__ Kb,
                      const short* __restrict__ Vt, const int* __restrict__ mask,
                      float* __restrict__ out) {
  __shared__ short Klds[16384];    // K 64x256, swizzled, 32KB
  __shared__ short Vlds[16384];    // V [256 d][64 k], swizzled, 32KB
  __shared__ short Plds[64 * 76];  // P 64 rows, stride 76 (conflict-free)
  const int bx = blockIdx.x;
  const int batch = bx & 3;
  const int q0 = (bx >> 2) * 64;
  const int tid = threadIdx.x;
  const int lane = tid & 63, quad = lane >> 4, c = lane & 15;
  const int w8 = tid >> 6, h = w8 >> 2, wc = w8 & 3;

  const short* kb = Kb + batch * 4096 * 256;
  const short* vb = Vt + batch * 1048576;
  const int* mb = mask + batch * 16777216;

  const int krow = tid >> 5;  // K staging row-in-16-row-line (0..15)
  const int kch = tid & 31;   // LDS chunk this thread fills

  // ---- prologue: K(0)->Klds, M(0)->mA, M(1)->mB, Q via asm ----
#pragma unroll
  for (int l = 0; l < 4; l++) {
    const int row = l * 16 + krow;
    const int chg = (kch & 16) | ((kch ^ row) & 15);  // involutive swizzle
    gl_lds16(kb + row * 256 + chg * 8, &Klds[l * 4096 + tid * 8]);
  }
  int mA[8], mB[8];
#pragma unroll
  for (int ms = 0; ms < 2; ms++)
#pragma unroll
    for (int r = 0; r < 4; r++) {
      const int qr = q0 + h * 32 + ms * 16 + quad * 4 + r;
      ld4nt(mA[ms * 4 + r], mb + qr * 4096 + wc * 16 + c);
      ld4nt(mB[ms * 4 + r], mb + qr * 4096 + 64 + wc * 16 + c);
    }
  bf8 aq[2][8];
  const short* qb = Qs + (batch * 4096 + q0) * 256;
#pragma unroll
  for (int ms = 0; ms < 2; ms++)
#pragma unroll
    for (int ks = 0; ks < 8; ks++)
      ld16(aq[ms][ks], qb + (h * 32 + ms * 16 + c) * 256 + ks * 32 + quad * 8);

  const f4 z = {0.f, 0.f, 0.f, 0.f};
  f4 accO[2][4], lacc[2];
#pragma unroll
  for (int ms = 0; ms < 2; ms++) {
    lacc[ms] = z;
#pragma unroll
    for (int ds = 0; ds < 4; ds++) accO[ms][ds] = z;
  }
  const bf8 ONES = {0x3F80, 0x3F80, 0x3F80, 0x3F80, 0x3F80, 0x3F80, 0x3F80, 0x3F80};

  // drain prologue; tie aq on the waitcnt, masks on a follow-up tie asm
  __asm__ __volatile__("s_waitcnt vmcnt(0)\ns_barrier"
      : "+v"(aq[0][0]), "+v"(aq[0][1]), "+v"(aq[0][2]), "+v"(aq[0][3]),
        "+v"(aq[0][4]), "+v"(aq[0][5]), "+v"(aq[0][6]), "+v"(aq[0][7]),
        "+v"(aq[1][0]), "+v"(aq[1][1]), "+v"(aq[1][2]), "+v"(aq[1][3]),
        "+v"(aq[1][4]), "+v"(aq[1][5]), "+v"(aq[1][6]), "+v"(aq[1][7])
      :: "memory");
  __asm__ __volatile__(""
      : "+v"(mA[0]), "+v"(mA[1]), "+v"(mA[2]), "+v"(mA[3]),
        "+v"(mA[4]), "+v"(mA[5]), "+v"(mA[6]), "+v"(mA[7]),
        "+v"(mB[0]), "+v"(mB[1]), "+v"(mB[2]), "+v"(mB[3]),
        "+v"(mB[4]), "+v"(mB[5]), "+v"(mB[6]), "+v"(mB[7]) :: "memory");

  auto tile = [&](int t, int* mcur) {
    // ---- A: stage V(t) -> Vlds[d][k], coalesced, swizzled (chunk^d&7).
    //      Vlds free: B1(t-1) proved all PV(t-1) reads done. ----
    const short* vbt = vb + t * 16384;
#pragma unroll
    for (int l = 0; l < 4; l++) {
      const int flat = l * 512 + tid;      // 0..2047, 16B each
      const int d = flat >> 3, ck = flat & 7;
      gl_lds16(vbt + d * 64 + ((ck ^ (d & 7)) << 3), &Vlds[flat * 8]);
    }

    // ---- S = Q' K^T from swizzled Klds (K(t) proven by prev B1) ----
    f4 s[2];
#pragma unroll
    for (int ms = 0; ms < 2; ms++) s[ms] = z;
#pragma unroll
    for (int ks = 0; ks < 8; ks++) {
      const int ch = ks * 4 + quad;
      const int sw = (ch & 16) | ((ch ^ c) & 15);
      const bf8 kf = *(const bf8*)&Klds[(wc * 16 + c) * 256 + sw * 8];
#pragma unroll
      for (int ms = 0; ms < 2; ms++) s[ms] = mfma16(aq[ms][ks], kf, s[ms]);
    }

    // ---- P = exp2(masked S) -> Plds (mask regs retired by prev vmcnt12) --
    short* pw = &Plds[0];
#pragma unroll
    for (int ms = 0; ms < 2; ms++)
#pragma unroll
      for (int r = 0; r < 4; r++) {
        float sv = (mcur[ms * 4 + r] != 0) ? s[ms][r] : -INFINITY;
        pw[(h * 32 + ms * 16 + quad * 4 + r) * 76 + wc * 16 + c] =
            f2bf(__builtin_amdgcn_exp2f(sv));
      }
    // B2: P visible; all QK reads of K(t) complete across the block
    __asm__ __volatile__("s_waitcnt lgkmcnt(0)\ns_barrier" ::: "memory");

    // ---- stage K(t+1) into the SAME buffer (safe past B2) ----
    const int tk = (t < 63) ? t + 1 : 63;
    const short* kbt = kb + tk * 16384;
#pragma unroll
    for (int l = 0; l < 4; l++) {
      const int row = l * 16 + krow;
      const int chg = (kch & 16) | ((kch ^ row) & 15);
      gl_lds16(kbt + row * 256 + chg * 8, &Klds[l * 4096 + tid * 8]);
    }

    // ---- issue M(t+2) into mcur (P reads above done; reg WAR orders) ----
    const int tm = (t + 2 < 64) ? t + 2 : 63;
#pragma unroll
    for (int ms = 0; ms < 2; ms++)
#pragma unroll
      for (int r = 0; r < 4; r++)
        ld4nt(mcur[ms * 4 + r],
              mb + (q0 + h * 32 + ms * 16 + quad * 4 + r) * 4096 + tm * 64 +
                  wc * 16 + c);

    // ---- E: queue=[M(t+1):8,V(t):4,K(t+1):4,M(t+2):8]=24; vmcnt(12)
    //      retires M(t+1)+V(t); barrier -> V(t) visible block-wide ----
    __asm__ __volatile__("s_waitcnt vmcnt(12)\ns_barrier"
        : "+v"(mA[0]), "+v"(mA[1]), "+v"(mA[2]), "+v"(mA[3]),
          "+v"(mA[4]), "+v"(mA[5]), "+v"(mA[6]), "+v"(mA[7]),
          "+v"(mB[0]), "+v"(mB[1]), "+v"(mB[2]), "+v"(mB[3]),
          "+v"(mB[4]), "+v"(mB[5]), "+v"(mB[6]), "+v"(mB[7]) :: "memory");

    // ---- O += P V ; row-sum via ones-frag MFMA. V frags from Vlds:
    //      lane reads Vlds[d=wc*64+ds*16+c][(k2*4+quad)^(c&7) chunk] ----
#pragma unroll
    for (int k2 = 0; k2 < 2; k2++) {
      bf8 ap[2], vf[4];
#pragma unroll
      for (int ds = 0; ds < 4; ds++)
        vf[ds] = *(const bf8*)&Vlds[(wc * 64 + ds * 16 + c) * 64 +
                                    (((k2 * 4 + quad) ^ (c & 7)) << 3)];
#pragma unroll
      for (int ms = 0; ms < 2; ms++)  // A[m=lane&15][k=quad*8+j]
        ap[ms] = *(const bf8*)&pw[(h * 32 + ms * 16 + c) * 76 + k2 * 32 +
                                  quad * 8];
#pragma unroll
      for (int ms = 0; ms < 2; ms++) {
        lacc[ms] = mfma16(ap[ms], ONES, lacc[ms]);
#pragma unroll
        for (int ds = 0; ds < 4; ds++)
          accO[ms][ds] = mfma16(ap[ms], vf[ds], accO[ms][ds]);
      }
    }
    // B1: K(t+1) landed (vmcnt 12->8 retires own K chunks); M(t+2) keeps
    // flying; all PV reads done -> next tile may overwrite Vlds/Plds
    __asm__ __volatile__("s_waitcnt vmcnt(8)\ns_barrier" ::: "memory");
  };

  for (int th = 0; th < 32; th++) {
    tile(2 * th, mA);
    tile(2 * th + 1, mB);
  }
  // drain in-flight tail M loads before epilogue reuses their registers
  __asm__ __volatile__("s_waitcnt vmcnt(0)" ::: "memory");

  // ---- epilogue: O / l (in-register, deterministic) ----
  float* ob = out + (batch * 4096 + q0) * 256;
#pragma unroll
  for (int ms = 0; ms < 2; ms++) {
    f4 rl;
#pragma unroll
    for (int r = 0; r < 4; r++) rl[r] = __builtin_amdgcn_rcpf(lacc[ms][r]);
#pragma unroll
    for (int ds = 0; ds < 4; ds++)
#pragma unroll
      for (int r = 0; r < 4; r++)
        ob[(h * 32 + ms * 16 + quad * 4 + r) * 256 + wc * 64 + ds * 16 + c] =
            accO[ms][ds][r] * rl[r];
  }
}

extern "C" void kernel_launch(void* const* d_in, const int* in_sizes, int n_in,
                              void* d_out, int out_size, void* d_ws, size_t ws_size,
                              hipStream_t stream) {
  const float* x = (const float*)d_in[0];
  const int* mask = (const int*)d_in[1];
  const float* Wq = (const float*)d_in[2];
  const float* bq = (const float*)d_in[3];
  const float* Wk = (const float*)d_in[4];
  const float* bk = (const float*)d_in[5];
  const float* Wv = (const float*)d_in[6];
  const float* bv = (const float*)d_in[7];
  float* out = (float*)d_out;

  char* ws = (char*)d_ws;  // 24 MiB + 384 KiB
  short* Qs = (short*)ws;
  short* Kb = (short*)(ws + (8u << 20));
  short* Vt = (short*)(ws + (16u << 20));
  short* Wp = (short*)(ws + (24u << 20));

  pack<<<96, 256, 0, stream>>>(Wq, Wk, Wv, Wp);
  qkv<<<dim3(512, 3), 256, 0, stream>>>(x, Wp, bq, bk, bv, Qs, Kb, Vt);
  flash<<<256, 512, 0, stream>>>(Qs, Kb, Vt, mask, out);
}

// Round 9
// 498.281 us; speedup vs baseline: 2.4954x; 1.0016x over previous
//
#include <hip/hip_runtime.h>

// Self-attention, B=4, N=4096, D=256 (single head over full D).
//   Q = x Wq^T + bq ; K,V likewise ; S = Q K^T ; mask==0 -> -inf ;
//   attn = softmax(S/16) ; out = attn V        (fp32 in/out)
// R19: R18 (K/V dbuf, new wait scheme) failed absmax 3.4e-3 -- second
//   failure of a freshly-derived vmcnt scheme (R14 was the first). Policy:
//   revert to R17 (passed, 181us) and change something sync-free.
//   Lever: XCD batch-locality. batch=bx&3 put all 4 batches on every XCD
//   (bx%8 round-robin) -> 16MB hot set vs 4MB L2 -> K/V rereads served by
//   ~10TB/s L3 (the R16/R17 wall). Remap batch=(bx&7)>>1: XCD pairs own
//   one batch; per-XCD K/V hot set = 4MB ~= L2. ~1GB of rereads move to
//   L2 (more BW, ~3x lower latency -> E/B1 waits shrink too).
//   q0=((bx>>3)*2+(bx&1))*64, bijective. Math/sync/data identical to R17.
// ws: Qs bf16 8MiB | Kb bf16 8MiB | Vt bf16 8MiB | Wp 384KiB

#define DEV static __device__ __forceinline__

typedef __attribute__((ext_vector_type(8))) short bf8;   // 8 bf16 (4 VGPR)
typedef __attribute__((ext_vector_type(4))) float f4;
typedef const __attribute__((address_space(1))) unsigned int* gp1;
typedef __attribute__((address_space(3))) unsigned int* lp3;

DEV short f2bf(float x) {  // fp32 -> bf16 RNE (inputs finite)
  unsigned u = __builtin_bit_cast(unsigned, x);
  u += 0x7FFFu + ((u >> 16) & 1u);
  return (short)(u >> 16);
}

DEV bf8 cvt8(f4 a, f4 b) {
  bf8 r;
  r[0] = f2bf(a[0]); r[1] = f2bf(a[1]); r[2] = f2bf(a[2]); r[3] = f2bf(a[3]);
  r[4] = f2bf(b[0]); r[5] = f2bf(b[1]); r[6] = f2bf(b[2]); r[7] = f2bf(b[3]);
  return r;
}

DEV bf8 cvtp(const float* p) { return cvt8(*(const f4*)p, *(const f4*)(p + 4)); }

DEV f4 mfma16(bf8 a, bf8 b, f4 c) {
  return __builtin_amdgcn_mfma_f32_16x16x32_bf16(a, b, c, 0, 0, 0);
}

DEV void gl_lds16(const void* g, void* l) {  // async global->LDS, 16B/lane
  __builtin_amdgcn_global_load_lds((gp1)g, (lp3)l, 16, 0, 0);
}

DEV void ld16(bf8& d, const short* p) {  // unsinkable 16B global load
  __asm__ __volatile__("global_load_dwordx4 %0, %1, off" : "=v"(d) : "v"(p));
}
DEV void ld4nt(int& d, const int* p) {   // unsinkable 4B global load, NT
  __asm__ __volatile__("global_load_dword %0, %1, off nt" : "=v"(d) : "v"(p));
}

// ---------------- kernel 0: pack W -> bf16 fragment-order (R9) ------------
__global__ void pack(const float* __restrict__ Wq, const float* __restrict__ Wk,
                     const float* __restrict__ Wv, short* __restrict__ Wp) {
  const int ch = blockIdx.x * 4 + (threadIdx.x >> 6);
  const int lane = threadIdx.x & 63;
  const int which = ch >> 7, rem = ch & 127;
  const int w = rem >> 5, e = (rem >> 3) & 3, ks = rem & 7;
  const float* W = (which == 0) ? Wq : (which == 1) ? Wk : Wv;
  bf8 v = cvtp(W + ((w * 4 + e) * 16 + (lane & 15)) * 256 + ks * 32 +
               (lane >> 4) * 8);
  *(bf8*)(Wp + ch * 512 + lane * 8) = v;
}

// ---------------- kernel 1: Q,K,V projection (R9) -------------------------
__launch_bounds__(256, 3)
__global__ void qkv(const float* __restrict__ x, const short* __restrict__ Wp,
                    const float* __restrict__ bq, const float* __restrict__ bk,
                    const float* __restrict__ bv, short* __restrict__ Qs,
                    short* __restrict__ Kb, short* __restrict__ Vt) {
  __shared__ float Xf[32 * 256];    // x tile, swizzled, 32KB
  __shared__ short Vlds[256 * 36];  // V transpose staging (which==2 only)
  const int which = blockIdx.y;
  const int m0 = blockIdx.x * 32;
  const int tid = threadIdx.x;
  const int w = tid >> 6, lane = tid & 63, quad = lane >> 4, c = lane & 15;
  const float* bias = (which == 0) ? bq : (which == 1) ? bk : bv;

#pragma unroll
  for (int l = 0; l < 8; l++) {
    const int row = l * 4 + (tid >> 6);
    const int kch = tid & 63;
    const int chg = (kch & 48) | ((kch ^ (row & 15)) & 15);  // involutive
    gl_lds16(x + (m0 + row) * 256 + chg * 4, &Xf[(l * 256 + tid) * 4]);
  }

  float bb[4];
#pragma unroll
  for (int e = 0; e < 4; e++) bb[e] = bias[(w * 4 + e) * 16 + c];

  f4 acc[2][4];
  const f4 z = {0.f, 0.f, 0.f, 0.f};
#pragma unroll
  for (int i = 0; i < 2; i++)
#pragma unroll
    for (int j = 0; j < 4; j++) acc[i][j] = z;

  __asm__ __volatile__("s_waitcnt vmcnt(0)\ns_barrier" ::: "memory");

  const short* wpb = Wp + (which * 4 + w) * 4 * 8 * 512;
#pragma unroll
  for (int ks = 0; ks < 8; ks++) {
    bf8 a[2], b[4];
#pragma unroll
    for (int ms = 0; ms < 2; ms++) {  // A[m=lane&15][k=quad*8+j]
      const int m = ms * 16 + c;
      const int ch0 = ks * 8 + quad * 2;
      const int sw0 = (ch0 & 48) | ((ch0 ^ c) & 15);
      const int sw1 = ((ch0 + 1) & 48) | (((ch0 + 1) ^ c) & 15);
      f4 f0 = *(const f4*)&Xf[m * 256 + sw0 * 4];
      f4 f1 = *(const f4*)&Xf[m * 256 + sw1 * 4];
      a[ms] = cvt8(f0, f1);
    }
#pragma unroll
    for (int e = 0; e < 4; e++)
      b[e] = *(const bf8*)(wpb + (e * 8 + ks) * 512 + lane * 8);
#pragma unroll
    for (int ms = 0; ms < 2; ms++)
#pragma unroll
      for (int e = 0; e < 4; e++) acc[ms][e] = mfma16(a[ms], b[e], acc[ms][e]);
  }

  const float sc = (which == 0) ? 0.09016844005556021f : 1.0f;  // log2e/16

  if (which < 2) {
    short* dst = (which == 0) ? Qs : Kb;
#pragma unroll
    for (int ms = 0; ms < 2; ms++)
#pragma unroll
      for (int e = 0; e < 4; e++)
#pragma unroll
        for (int r = 0; r < 4; r++)  // C/D: col=lane&15, row=quad*4+reg
          dst[(m0 + ms * 16 + quad * 4 + r) * 256 + (w * 4 + e) * 16 + c] =
              f2bf((acc[ms][e][r] + bb[e]) * sc);
  } else {
#pragma unroll
    for (int ms = 0; ms < 2; ms++)
#pragma unroll
      for (int e = 0; e < 4; e++)
#pragma unroll
        for (int r = 0; r < 4; r++)
          Vlds[((w * 4 + e) * 16 + c) * 36 + ms * 16 + quad * 4 + r] =
              f2bf(acc[ms][e][r] + bb[e]);
    __syncthreads();
    const int tt = m0 >> 6, half = m0 & 32;
#pragma unroll
    for (int j = 0; j < 4; j++) {
      int flat = j * 2048 + tid * 8;        // 256 d x 32 n
      int d = flat >> 5, n = flat & 31;
      *(bf8*)(Vt + tt * 16384 + d * 64 + half + n) =
          *(const bf8*)&Vlds[d * 36 + n];
    }
  }
}

// ---------------- kernel 2: flash attention ----------------
// 256 WGs x 512 threads (8 waves, 1 block/CU). XCD-batch mapping:
// batch = (bx&7)>>1 (XCD pair owns one batch -> per-XCD K/V hot set 4MB
// ~= L2), q0 = ((bx>>3)*2+(bx&1))*64. Wave w8: h = w8>>2 (q-rows
// h*32..+31), wc = w8&3 (cols wc*64..+63 for PV/out, k-cols wc*16..+15
// for QK/P). All K and V traffic via coalesced gl_lds16; NO strided
// register VM loads. Pipeline identical to R17 (proven):
//  A stage V(t) -> QK -> P -> B2(lgkm0+bar) -> stage K(t+1) -> M(t+2) NT
//  -> E vmcnt(12)+bar [V landed block-wide; retires M(t+1)] -> PV
//  (V,P from LDS) -> B1 vmcnt(8)+bar [K landed].
__launch_bounds__(512, 1)
__global__ void flash(const short* __restrict__ Qs, const short* __restrict__ Kb,
                      const short* __restrict__ Vt, const int* __restrict__ mask,
                      float* __restrict__ out) {
  __shared__ short Klds[16384];    // K 64x256, swizzled, 32KB
  __shared__ short Vlds[16384];    // V [256 d][64 k], swizzled, 32KB
  __shared__ short Plds[64 * 76];  // P 64 rows, stride 76 (conflict-free)
  const int bx = blockIdx.x;
  const int batch = (bx & 7) >> 1;                  // XCD pair -> batch
  const int q0 = ((bx >> 3) * 2 + (bx & 1)) * 64;   // bijective q-tile
  const int tid = threadIdx.x;
  const int lane = tid & 63, quad = lane >> 4, c = lane & 15;
  const int w8 = tid >> 6, h = w8 >> 2, wc = w8 & 3;

  const short* kb = Kb + batch * 4096 * 256;
  const short* vb = Vt + batch * 1048576;
  const int* mb = mask + batch * 16777216;

  const int krow = tid >> 5;  // K staging row-in-16-row-line (0..15)
  const int kch = tid & 31;   // LDS chunk this thread fills

  // ---- prologue: K(0)->Klds, M(0)->mA, M(1)->mB, Q via asm ----
#pragma unroll
  for (int l = 0; l < 4; l++) {
    const int row = l * 16 + krow;
    const int chg = (kch & 16) | ((kch ^ row) & 15);  // involutive swizzle
    gl_lds16(kb + row * 256 + chg * 8, &Klds[l * 4096 + tid * 8]);
  }
  int mA[8], mB[8];
#pragma unroll
  for (int ms = 0; ms < 2; ms++)
#pragma unroll
    for (int r = 0; r < 4; r++) {
      const int qr = q0 + h * 32 + ms * 16 + quad * 4 + r;
      ld4nt(mA[ms * 4 + r], mb + qr * 4096 + wc * 16 + c);
      ld4nt(mB[ms * 4 + r], mb + qr * 4096 + 64 + wc * 16 + c);
    }
  bf8 aq[2][8];
  const short* qb = Qs + (batch * 4096 + q0) * 256;
#pragma unroll
  for (int ms = 0; ms < 2; ms++)
#pragma unroll
    for (int ks = 0; ks < 8; ks++)
      ld16(aq[ms][ks], qb + (h * 32 + ms * 16 + c) * 256 + ks * 32 + quad * 8);

  const f4 z = {0.f, 0.f, 0.f, 0.f};
  f4 accO[2][4], lacc[2];
#pragma unroll
  for (int ms = 0; ms < 2; ms++) {
    lacc[ms] = z;
#pragma unroll
    for (int ds = 0; ds < 4; ds++) accO[ms][ds] = z;
  }
  const bf8 ONES = {0x3F80, 0x3F80, 0x3F80, 0x3F80, 0x3F80, 0x3F80, 0x3F80, 0x3F80};

  // drain prologue; tie aq on the waitcnt, masks on a follow-up tie asm
  __asm__ __volatile__("s_waitcnt vmcnt(0)\ns_barrier"
      : "+v"(aq[0][0]), "+v"(aq[0][1]), "+v"(aq[0][2]), "+v"(aq[0][3]),
        "+v"(aq[0][4]), "+v"(aq[0][5]), "+v"(aq[0][6]), "+v"(aq[0][7]),
        "+v"(aq[1][0]), "+v"(aq[1][1]), "+v"(aq[1][2]), "+v"(aq[1][3]),
        "+v"(aq[1][4]), "+v"(aq[1][5]), "+v"(aq[1][6]), "+v"(aq[1][7])
      :: "memory");
  __asm__ __volatile__(""
      : "+v"(mA[0]), "+v"(mA[1]), "+v"(mA[2]), "+v"(mA[3]),
        "+v"(mA[4]), "+v"(mA[5]), "+v"(mA[6]), "+v"(mA[7]),
        "+v"(mB[0]), "+v"(mB[1]), "+v"(mB[2]), "+v"(mB[3]),
        "+v"(mB[4]), "+v"(mB[5]), "+v"(mB[6]), "+v"(mB[7]) :: "memory");

  auto tile = [&](int t, int* mcur) {
    // ---- A: stage V(t) -> Vlds[d][k], coalesced, swizzled (chunk^d&7).
    //      Vlds free: B1(t-1) proved all PV(t-1) reads done. ----
    const short* vbt = vb + t * 16384;
#pragma unroll
    for (int l = 0; l < 4; l++) {
      const int flat = l * 512 + tid;      // 0..2047, 16B each
      const int d = flat >> 3, ck = flat & 7;
      gl_lds16(vbt + d * 64 + ((ck ^ (d & 7)) << 3), &Vlds[flat * 8]);
    }

    // ---- S = Q' K^T from swizzled Klds (K(t) proven by prev B1) ----
    f4 s[2];
#pragma unroll
    for (int ms = 0; ms < 2; ms++) s[ms] = z;
#pragma unroll
    for (int ks = 0; ks < 8; ks++) {
      const int ch = ks * 4 + quad;
      const int sw = (ch & 16) | ((ch ^ c) & 15);
      const bf8 kf = *(const bf8*)&Klds[(wc * 16 + c) * 256 + sw * 8];
#pragma unroll
      for (int ms = 0; ms < 2; ms++) s[ms] = mfma16(aq[ms][ks], kf, s[ms]);
    }

    // ---- P = exp2(masked S) -> Plds (mask regs retired by prev vmcnt12) --
    short* pw = &Plds[0];
#pragma unroll
    for (int ms = 0; ms < 2; ms++)
#pragma unroll
      for (int r = 0; r < 4; r++) {
        float sv = (mcur[ms * 4 + r] != 0) ? s[ms][r] : -INFINITY;
        pw[(h * 32 + ms * 16 + quad * 4 + r) * 76 + wc * 16 + c] =
            f2bf(__builtin_amdgcn_exp2f(sv));
      }
    // B2: P visible; all QK reads of K(t) complete across the block
    __asm__ __volatile__("s_waitcnt lgkmcnt(0)\ns_barrier" ::: "memory");

    // ---- stage K(t+1) into the SAME buffer (safe past B2) ----
    const int tk = (t < 63) ? t + 1 : 63;
    const short* kbt = kb + tk * 16384;
#pragma unroll
    for (int l = 0; l < 4; l++) {
      const int row = l * 16 + krow;
      const int chg = (kch & 16) | ((kch ^ row) & 15);
      gl_lds16(kbt + row * 256 + chg * 8, &Klds[l * 4096 + tid * 8]);
    }

    // ---- issue M(t+2) into mcur (P reads above done; reg WAR orders) ----
    const int tm = (t + 2 < 64) ? t + 2 : 63;
#pragma unroll
    for (int ms = 0; ms < 2; ms++)
#pragma unroll
      for (int r = 0; r < 4; r++)
        ld4nt(mcur[ms * 4 + r],
              mb + (q0 + h * 32 + ms * 16 + quad * 4 + r) * 4096 + tm * 64 +
                  wc * 16 + c);

    // ---- E: queue=[M(t+1):8,V(t):4,K(t+1):4,M(t+2):8]=24; vmcnt(12)
    //      retires M(t+1)+V(t); barrier -> V(t) visible block-wide ----
    __asm__ __volatile__("s_waitcnt vmcnt(12)\ns_barrier"
        : "+v"(mA[0]), "+v"(mA[1]), "+v"(mA[2]), "+v"(mA[3]),
          "+v"(mA[4]), "+v"(mA[5]), "+v"(mA[6]), "+v"(mA[7]),
          "+v"(mB[0]), "+v"(mB[1]), "+v"(mB[2]), "+v"(mB[3]),
          "+v"(mB[4]), "+v"(mB[5]), "+v"(mB[6]), "+v"(mB[7]) :: "memory");

    // ---- O += P V ; row-sum via ones-frag MFMA. V frags from Vlds:
    //      lane reads Vlds[d=wc*64+ds*16+c][(k2*4+quad)^(c&7) chunk] ----
#pragma unroll
    for (int k2 = 0; k2 < 2; k2++) {
      bf8 ap[2], vf[4];
#pragma unroll
      for (int ds = 0; ds < 4; ds++)
        vf[ds] = *(const bf8*)&Vlds[(wc * 64 + ds * 16 + c) * 64 +
                                    (((k2 * 4 + quad) ^ (c & 7)) << 3)];
#pragma unroll
      for (int ms = 0; ms < 2; ms++)  // A[m=lane&15][k=quad*8+j]
        ap[ms] = *(const bf8*)&pw[(h * 32 + ms * 16 + c) * 76 + k2 * 32 +
                                  quad * 8];
#pragma unroll
      for (int ms = 0; ms < 2; ms++) {
        lacc[ms] = mfma16(ap[ms], ONES, lacc[ms]);
#pragma unroll
        for (int ds = 0; ds < 4; ds++)
          accO[ms][ds] = mfma16(ap[ms], vf[ds], accO[ms][ds]);
      }
    }
    // B1: K(t+1) landed (vmcnt 12->8 retires own K chunks); M(t+2) keeps
    // flying; all PV reads done -> next tile may overwrite Vlds/Plds
    __asm__ __volatile__("s_waitcnt vmcnt(8)\ns_barrier" ::: "memory");
  };

  for (int th = 0; th < 32; th++) {
    tile(2 * th, mA);
    tile(2 * th + 1, mB);
  }
  // drain in-flight tail M loads before epilogue reuses their registers
  __asm__ __volatile__("s_waitcnt vmcnt(0)" ::: "memory");

  // ---- epilogue: O / l (in-register, deterministic) ----
  float* ob = out + (batch * 4096 + q0) * 256;
#pragma unroll
  for (int ms = 0; ms < 2; ms++) {
    f4 rl;
#pragma unroll
    for (int r = 0; r < 4; r++) rl[r] = __builtin_amdgcn_rcpf(lacc[ms][r]);
#pragma unroll
    for (int ds = 0; ds < 4; ds++)
#pragma unroll
      for (int r = 0; r < 4; r++)
        ob[(h * 32 + ms * 16 + quad * 4 + r) * 256 + wc * 64 + ds * 16 + c] =
            accO[ms][ds][r] * rl[r];
  }
}

extern "C" void kernel_launch(void* const* d_in, const int* in_sizes, int n_in,
                              void* d_out, int out_size, void* d_ws, size_t ws_size,
                              hipStream_t stream) {
  const float* x = (const float*)d_in[0];
  const int* mask = (const int*)d_in[1];
  const float* Wq = (const float*)d_in[2];
  const float* bq = (const float*)d_in[3];
  const float* Wk = (const float*)d_in[4];
  const float* bk = (const float*)d_in[5];
  const float* Wv = (const float*)d_in[6];
  const float* bv = (const float*)d_in[7];
  float* out = (float*)d_out;

  char* ws = (char*)d_ws;  // 24 MiB + 384 KiB
  short* Qs = (short*)ws;
  short* Kb = (short*)(ws + (8u << 20));
  short* Vt = (short*)(ws + (16u << 20));
  short* Wp = (short*)(ws + (24u << 20));

  pack<<<96, 256, 0, stream>>>(Wq, Wk, Wv, Wp);
  qkv<<<dim3(512, 3), 256, 0, stream>>>(x, Wp, bq, bk, bv, Qs, Kb, Vt);
  flash<<<256, 512, 0, stream>>>(Qs, Kb, Vt, mask, out);
}